// Round 5
// baseline (20471.442 us; speedup 1.0000x reference)
//
#include <hip/hip_runtime.h>
#include <cstdint>
#include <cstddef>

#define T_LEN 8192
#define EMB 256
#define HD 256          // hidden per direction
#define G4 1024         // 4*HD
#define NT 16
#define START_IX 14
#define STOP_IX 15

// ---------------------------------------------------------------------------
// Phase A: xw[dir][t][r] = emb[dir? T-1-t : t] @ w_ih^T + (b_ih + b_hh)
// grid (T/32, G4/128, 2), block 256   (round-1 version, proven)
// ---------------------------------------------------------------------------
__global__ __launch_bounds__(256) void k_gemm_xw(
    const int* __restrict__ sent, const float* __restrict__ embed,
    const float* __restrict__ wih_f, const float* __restrict__ wih_b,
    const float* __restrict__ bih_f, const float* __restrict__ bhh_f,
    const float* __restrict__ bih_b, const float* __restrict__ bhh_b,
    float* __restrict__ xw)
{
    const int dir = blockIdx.z;
    const float* __restrict__ wih = dir ? wih_b : wih_f;
    const float* __restrict__ bih = dir ? bih_b : bih_f;
    const float* __restrict__ bhh = dir ? bhh_b : bhh_f;
    __shared__ float at[32][65];
    __shared__ float bt[128][65];
    const int t0 = blockIdx.x * 32, r0 = blockIdx.y * 128;
    const int tid = threadIdx.x;
    const int tx = tid & 31, ty = tid >> 5;
    float acc[4][4] = {};
    for (int k0 = 0; k0 < EMB; k0 += 64) {
        for (int i = tid; i < 32 * 64; i += 256) {
            int row = i >> 6, k = i & 63;
            int t = t0 + row;
            int ts = dir ? (T_LEN - 1 - t) : t;
            at[row][k] = embed[(size_t)sent[ts] * EMB + k0 + k];
        }
        for (int i = tid; i < 128 * 64; i += 256) {
            int row = i >> 6, k = i & 63;
            bt[row][k] = wih[(size_t)(r0 + row) * EMB + k0 + k];
        }
        __syncthreads();
#pragma unroll 16
        for (int kc = 0; kc < 64; ++kc) {
            float a[4], b[4];
#pragma unroll
            for (int u = 0; u < 4; ++u) a[u] = at[ty * 4 + u][kc];
#pragma unroll
            for (int u = 0; u < 4; ++u) b[u] = bt[tx * 4 + u][kc];
#pragma unroll
            for (int u = 0; u < 4; ++u)
#pragma unroll
                for (int v = 0; v < 4; ++v) acc[u][v] += a[u] * b[v];
        }
        __syncthreads();
    }
#pragma unroll
    for (int u = 0; u < 4; ++u) {
        int t = t0 + ty * 4 + u;
#pragma unroll
        for (int v = 0; v < 4; ++v) {
            int r = r0 + tx * 4 + v;
            xw[((size_t)dir * T_LEN + t) * G4 + r] = acc[u][v] + bih[r] + bhh[r];
        }
    }
}

// ---------------------------------------------------------------------------
// Phase B: LSTM scans. grid 8 (= dir*4 + w), block 1024 (16 waves).
// Transport = round-2 proven mechanism: h_hist pre-poisoned to 0xFFFFFFFF
// (-NaN, unreachable from finite arithmetic); producer stores h words with
// relaxed AGENT-scope atomics (MALL coherence point -- known working on this
// chip); consumers poll the h words themselves. Each (t,j) word is written
// exactly once per launch -> no parity buffers, no ABA, no flags.
// Layout = round-4 geometry: 4 WGs/dir, 64-wide slices, only 3 remote
// slices to poll, full-wave producer.
// Roles per step (after B1):
//   wave 0    : reduce 16 partials/lane, 4 gates, c/h update, h_lds + 1
//               agent store of own slice word
//   waves 1-3 : poll the 3 remote 64-wide slices -> h_lds
//   waves 4-7 : prefetch xw[t+1] -> xw_lds[nxt]
//   waves 8-15: matvec only
// Skew-lock: WG A's B2(t) requires all 3 remote t-slices; every producer
// stores t only after its B1(t); so all 4 WGs of a direction stay within
// one step of each other, and each h word is read only after written.
// ---------------------------------------------------------------------------
__global__ __launch_bounds__(1024) void k_lstm(
    const float* __restrict__ whh_f, const float* __restrict__ whh_b,
    const float* __restrict__ h0, const float* __restrict__ c0,
    const float* __restrict__ xw, float* __restrict__ h_hist)
{
    const int role = blockIdx.x;     // 0..7, deterministic
    const int dir = role >> 2, w = role & 3;
    const float* __restrict__ whh = dir ? whh_b : whh_f;
    const int tid = threadIdx.x;
    const int q = tid >> 8;          // k-quarter 0..3
    const int r = tid & 255;         // local gate-row 0..255 (= g*64 + j)
    const int R = (r >> 6) * 256 + w * 64 + (r & 63);   // global gate-row

    __shared__ float h_lds[256];
    __shared__ float partial[1024];
    __shared__ float xw_lds[2][256];

    float4 wreg[16];
    {
        const float4* wp = (const float4*)&whh[(size_t)R * HD + q * 64];
#pragma unroll
        for (int u = 0; u < 16; ++u) wreg[u] = wp[u];
    }

    if (tid < 256) {
        h_lds[tid] = h0[dir * HD + tid];
        xw_lds[0][tid] = xw[((size_t)dir * T_LEN) * G4
                            + (tid >> 6) * 256 + w * 64 + (tid & 63)];
    }

    const int wave = tid >> 6;
    const int lane = tid & 63;
    float c = 0.f;
    if (wave == 0) c = c0[dir * HD + w * 64 + lane];

    int ps = 0;                      // remote slice polled by waves 1-3
    if (wave >= 1 && wave <= 3) ps = (wave - 1) + ((wave - 1) >= w ? 1 : 0);

    __syncthreads();

    float* __restrict__ hh = h_hist + (size_t)dir * T_LEN * HD;

    for (int t = 0; t < T_LEN; ++t) {
        const int cur = t & 1, nxt = cur ^ 1;

        // matvec partial over this thread's k-quarter; h_lds reads are
        // wave-uniform broadcasts (q constant within a wave)
        float a0 = 0.f, a1 = 0.f, a2 = 0.f, a3 = 0.f;
        const float4* hp = (const float4*)&h_lds[q * 64];
#pragma unroll
        for (int u = 0; u < 4; ++u) {
            float4 hv0 = hp[u * 4 + 0], hv1 = hp[u * 4 + 1];
            float4 hv2 = hp[u * 4 + 2], hv3 = hp[u * 4 + 3];
            float4 wv0 = wreg[u * 4 + 0], wv1 = wreg[u * 4 + 1];
            float4 wv2 = wreg[u * 4 + 2], wv3 = wreg[u * 4 + 3];
            a0 += wv0.x * hv0.x + wv0.y * hv0.y + wv0.z * hv0.z + wv0.w * hv0.w;
            a1 += wv1.x * hv1.x + wv1.y * hv1.y + wv1.z * hv1.z + wv1.w * hv1.w;
            a2 += wv2.x * hv2.x + wv2.y * hv2.y + wv2.z * hv2.z + wv2.w * hv2.w;
            a3 += wv3.x * hv3.x + wv3.y * hv3.y + wv3.z * hv3.z + wv3.w * hv3.w;
        }
        partial[tid] = (a0 + a1) + (a2 + a3);   // partial[q*256 + g*64 + j]
        __syncthreads();   // B1

        if (wave == 0) {
            const int j = lane;
            float zi = xw_lds[cur][0 * 64 + j] + partial[0 * 64 + j]
                     + partial[256 + 0 * 64 + j] + partial[512 + 0 * 64 + j]
                     + partial[768 + 0 * 64 + j];
            float zf = xw_lds[cur][1 * 64 + j] + partial[1 * 64 + j]
                     + partial[256 + 1 * 64 + j] + partial[512 + 1 * 64 + j]
                     + partial[768 + 1 * 64 + j];
            float zg = xw_lds[cur][2 * 64 + j] + partial[2 * 64 + j]
                     + partial[256 + 2 * 64 + j] + partial[512 + 2 * 64 + j]
                     + partial[768 + 2 * 64 + j];
            float zo = xw_lds[cur][3 * 64 + j] + partial[3 * 64 + j]
                     + partial[256 + 3 * 64 + j] + partial[512 + 3 * 64 + j]
                     + partial[768 + 3 * 64 + j];
            float iv = 1.f / (1.f + expf(-zi));
            float fv = 1.f / (1.f + expf(-zf));
            float gv = tanhf(zg);
            float ov = 1.f / (1.f + expf(-zo));
            c = fv * c + iv * gv;
            float hv = ov * tanhf(c);
            h_lds[w * 64 + j] = hv;
            __hip_atomic_store((unsigned*)&hh[(size_t)t * HD + w * 64 + j],
                               __float_as_uint(hv),
                               __ATOMIC_RELAXED, __HIP_MEMORY_SCOPE_AGENT);
        } else if (wave <= 3) {
            const unsigned* src =
                (const unsigned*)&hh[(size_t)t * HD + ps * 64 + lane];
            unsigned v; int spin = 0;
            do {
                v = __hip_atomic_load(src, __ATOMIC_RELAXED,
                                      __HIP_MEMORY_SCOPE_AGENT);
            } while (v == 0xFFFFFFFFu && ++spin < (1 << 20));  // safety cap
            h_lds[ps * 64 + lane] = __uint_as_float(v);
        } else if (wave <= 7) {
            const int i = (wave - 4) * 64 + lane;
            if (t + 1 < T_LEN)
                xw_lds[nxt][i] = xw[((size_t)dir * T_LEN + (t + 1)) * G4
                                    + (i >> 6) * 256 + w * 64 + (i & 63)];
        }
        __syncthreads();   // B2
    }
}

// ---------------------------------------------------------------------------
// Phase C: feats. One thread per t computes all 16 tags; W_out staged in
// LDS (32 KB) -> h_hist read exactly once. grid 32, block 256.
// ---------------------------------------------------------------------------
__global__ __launch_bounds__(256) void k_feats(
    const float* __restrict__ h_hist, const float* __restrict__ Wout,
    const float* __restrict__ bout, float* __restrict__ feats)
{
    __shared__ float wlds[16][512];
    const int tid = threadIdx.x;
    for (int i = tid; i < 16 * 512; i += 256) wlds[i >> 9][i & 511] = Wout[i];
    __syncthreads();
    const int t = blockIdx.x * 256 + tid;
    const float4* hf = (const float4*)(h_hist + (size_t)t * HD);
    const float4* hb = (const float4*)(h_hist + (size_t)(T_LEN + (T_LEN - 1 - t)) * HD);
    float acc[16];
#pragma unroll
    for (int g = 0; g < 16; ++g) acc[g] = bout[g];
    for (int k = 0; k < 64; ++k) {
        float4 a = hf[k];
#pragma unroll
        for (int g = 0; g < 16; ++g) {
            float4 b = *(const float4*)&wlds[g][k * 4];
            acc[g] += a.x * b.x + a.y * b.y + a.z * b.z + a.w * b.w;
        }
    }
    for (int k = 0; k < 64; ++k) {
        float4 a = hb[k];
#pragma unroll
        for (int g = 0; g < 16; ++g) {
            float4 b = *(const float4*)&wlds[g][256 + k * 4];
            acc[g] += a.x * b.x + a.y * b.y + a.z * b.z + a.w * b.w;
        }
    }
#pragma unroll
    for (int g = 0; g < 16; ++g) feats[(size_t)t * NT + g] = acc[g];
}

// ---------------------------------------------------------------------------
// Phase D: Viterbi (round-3 version: register fv + shfl, fp64, prefetch;
// proven bit-exact path).
// ---------------------------------------------------------------------------
__device__ __forceinline__ unsigned bsel16(uint4 g, unsigned e) {
    unsigned wd = (e < 8u) ? ((e < 4u) ? g.x : g.y) : ((e < 12u) ? g.z : g.w);
    return (wd >> ((e & 3u) * 8u)) & 15u;
}

__global__ __launch_bounds__(256) void k_viterbi(
    const float* __restrict__ feats, const float* __restrict__ trans,
    int* __restrict__ out, unsigned char* __restrict__ bp)
{
    __shared__ int sid;
    __shared__ unsigned slo[512], shi[512];
    const int tid = threadIdx.x;

    if (tid < 64) {
        const int i = tid & 15, jg = tid >> 4;
        double tr[4];
#pragma unroll
        for (int u = 0; u < 4; ++u) tr[u] = (double)trans[i * 16 + jg * 4 + u];
        double fvn = (i == START_IX) ? 0.0 : -10000.0;
        float fA = feats[i];
        float fB = feats[16 + i];

        for (int t = 0; t < T_LEN; ++t) {
            float fC = (t + 2 < T_LEN) ? feats[(size_t)(t + 2) * NT + i] : 0.f;

            double best = -1e300; int bj = 0;
#pragma unroll
            for (int u = 0; u < 4; ++u) {
                double fvv = __shfl(fvn, jg * 4 + u);
                double v = fvv + tr[u];
                if (v > best) { best = v; bj = jg * 4 + u; }   // first-max
            }
            double ob = __shfl_down(best, 32); int oj = __shfl_down(bj, 32);
            if (ob > best || (ob == best && oj < bj)) { best = ob; bj = oj; }
            ob = __shfl_down(best, 16); oj = __shfl_down(bj, 16);
            if (ob > best || (ob == best && oj < bj)) { best = ob; bj = oj; }

            if (tid < 16) {
                bp[(size_t)t * 16 + i] = (unsigned char)bj;
                fvn = (double)fA + best;
            }
            fA = fB; fB = fC;
        }
        double term = (tid < 16) ? fvn + (double)trans[tid * 16 + STOP_IX] : -1e300;
        int ti = tid;
#pragma unroll
        for (int off = 1; off < 16; off <<= 1) {
            double ov = __shfl_xor(term, off); int oi = __shfl_xor(ti, off);
            if (ov > term || (ov == term && oi < ti)) { term = ov; ti = oi; }
        }
        if (tid == 0) sid = ti;
    }
    __syncthreads();

    const int j = tid;
    unsigned Flo = 0x76543210u, Fhi = 0xfedcba98u;
    for (int t = 32 * j + 31; t >= 32 * j; --t) {
        uint4 g = *(const uint4*)&bp[(size_t)t * 16];
        unsigned nlo = 0, nhi = 0;
#pragma unroll
        for (int x = 0; x < 8; ++x) {
            unsigned e = (Flo >> (x * 4)) & 15u;
            nlo |= bsel16(g, e) << (x * 4);
        }
#pragma unroll
        for (int x = 0; x < 8; ++x) {
            unsigned e = (Fhi >> (x * 4)) & 15u;
            nhi |= bsel16(g, e) << (x * 4);
        }
        Flo = nlo; Fhi = nhi;
    }
    slo[j] = Flo; shi[j] = Fhi;
    slo[j + 256] = 0x76543210u; shi[j + 256] = 0xfedcba98u;
    __syncthreads();
    for (int off = 1; off < 256; off <<= 1) {
        unsigned alo = slo[j], ahi = shi[j];
        unsigned blo = slo[j + off], bhi = shi[j + off];
        __syncthreads();
        unsigned nlo = 0, nhi = 0;
#pragma unroll
        for (int x = 0; x < 8; ++x) {
            unsigned e = (blo >> (x * 4)) & 15u;
            unsigned rr = ((e < 8u ? alo : ahi) >> ((e & 7u) * 4u)) & 15u;
            nlo |= rr << (x * 4);
        }
#pragma unroll
        for (int x = 0; x < 8; ++x) {
            unsigned e = (bhi >> (x * 4)) & 15u;
            unsigned rr = ((e < 8u ? alo : ahi) >> ((e & 7u) * 4u)) & 15u;
            nhi |= rr << (x * 4);
        }
        slo[j] = nlo; shi[j] = nhi;
        __syncthreads();
    }
    int idl = sid;
    unsigned plo = slo[j + 1], phi = shi[j + 1];
    unsigned x = (((unsigned)idl < 8u ? plo : phi) >> (((unsigned)idl & 7u) * 4u)) & 15u;
    out[32 * j + 31] = (int)x;
    for (int t = 32 * j + 30; t >= 32 * j; --t) {
        x = (unsigned)bp[(size_t)(t + 1) * 16 + x];
        out[t] = (int)x;
    }
}

// ---------------------------------------------------------------------------
extern "C" void kernel_launch(void* const* d_in, const int* in_sizes, int n_in,
                              void* d_out, int out_size, void* d_ws, size_t ws_size,
                              hipStream_t stream) {
    const int*   sent  = (const int*)  d_in[0];
    const float* embed = (const float*)d_in[1];
    const float* wih_f = (const float*)d_in[2];
    const float* whh_f = (const float*)d_in[3];
    const float* bih_f = (const float*)d_in[4];
    const float* bhh_f = (const float*)d_in[5];
    const float* wih_b = (const float*)d_in[6];
    const float* whh_b = (const float*)d_in[7];
    const float* bih_b = (const float*)d_in[8];
    const float* bhh_b = (const float*)d_in[9];
    const float* Wout  = (const float*)d_in[10];
    const float* bout  = (const float*)d_in[11];
    const float* trans = (const float*)d_in[12];
    const float* h0    = (const float*)d_in[13];
    const float* c0    = (const float*)d_in[14];
    int* out = (int*)d_out;

    float* ws_xw   = (float*)d_ws;                                  // 2*T*1024 f
    float* ws_h    = ws_xw + (size_t)2 * T_LEN * G4;                // 2*T*256 f
    float* ws_feat = ws_h + (size_t)2 * T_LEN * HD;                 // T*16 f
    unsigned char* ws_bp = (unsigned char*)(ws_feat + (size_t)T_LEN * NT); // T*16 B

    // sentinel-fill h_hist every launch: 0xFFFFFFFF (-NaN) is unreachable
    // from finite arithmetic; each word is then written exactly once.
    hipMemsetAsync(ws_h, 0xFF, (size_t)2 * T_LEN * HD * sizeof(float), stream);

    dim3 gA(T_LEN / 32, G4 / 128, 2);
    k_gemm_xw<<<gA, 256, 0, stream>>>(sent, embed, wih_f, wih_b,
                                      bih_f, bhh_f, bih_b, bhh_b, ws_xw);
    k_lstm<<<8, 1024, 0, stream>>>(whh_f, whh_b, h0, c0, ws_xw, ws_h);
    k_feats<<<32, 256, 0, stream>>>(ws_h, Wout, bout, ws_feat);
    k_viterbi<<<1, 256, 0, stream>>>(ws_feat, trans, out, ws_bp);
}

// Round 7
// 19476.900 us; speedup vs baseline: 1.0511x; 1.0511x over previous
//
#include <hip/hip_runtime.h>
#include <cstdint>
#include <cstddef>

#define T_LEN 8192
#define EMB 256
#define HD 256          // hidden per direction
#define G4 1024         // 4*HD
#define NT 16
#define START_IX 14
#define STOP_IX 15

// ---------------------------------------------------------------------------
// Phase A: xw[dir][t][r] = emb[dir? T-1-t : t] @ w_ih^T + (b_ih + b_hh)
// grid (T/32, G4/128, 2), block 256   (proven)
// ---------------------------------------------------------------------------
__global__ __launch_bounds__(256) void k_gemm_xw(
    const int* __restrict__ sent, const float* __restrict__ embed,
    const float* __restrict__ wih_f, const float* __restrict__ wih_b,
    const float* __restrict__ bih_f, const float* __restrict__ bhh_f,
    const float* __restrict__ bih_b, const float* __restrict__ bhh_b,
    float* __restrict__ xw)
{
    const int dir = blockIdx.z;
    const float* __restrict__ wih = dir ? wih_b : wih_f;
    const float* __restrict__ bih = dir ? bih_b : bih_f;
    const float* __restrict__ bhh = dir ? bhh_b : bhh_f;
    __shared__ float at[32][65];
    __shared__ float bt[128][65];
    const int t0 = blockIdx.x * 32, r0 = blockIdx.y * 128;
    const int tid = threadIdx.x;
    const int tx = tid & 31, ty = tid >> 5;
    float acc[4][4] = {};
    for (int k0 = 0; k0 < EMB; k0 += 64) {
        for (int i = tid; i < 32 * 64; i += 256) {
            int row = i >> 6, k = i & 63;
            int t = t0 + row;
            int ts = dir ? (T_LEN - 1 - t) : t;
            at[row][k] = embed[(size_t)sent[ts] * EMB + k0 + k];
        }
        for (int i = tid; i < 128 * 64; i += 256) {
            int row = i >> 6, k = i & 63;
            bt[row][k] = wih[(size_t)(r0 + row) * EMB + k0 + k];
        }
        __syncthreads();
#pragma unroll 16
        for (int kc = 0; kc < 64; ++kc) {
            float a[4], b[4];
#pragma unroll
            for (int u = 0; u < 4; ++u) a[u] = at[ty * 4 + u][kc];
#pragma unroll
            for (int u = 0; u < 4; ++u) b[u] = bt[tx * 4 + u][kc];
#pragma unroll
            for (int u = 0; u < 4; ++u)
#pragma unroll
                for (int v = 0; v < 4; ++v) acc[u][v] += a[u] * b[v];
        }
        __syncthreads();
    }
#pragma unroll
    for (int u = 0; u < 4; ++u) {
        int t = t0 + ty * 4 + u;
#pragma unroll
        for (int v = 0; v < 4; ++v) {
            int r = r0 + tx * 4 + v;
            xw[((size_t)dir * T_LEN + t) * G4 + r] = acc[u][v] + bih[r] + bhh[r];
        }
    }
}

// ---------------------------------------------------------------------------
// Phase B: LSTM scans. grid 8 (= dir*4 + w), block 512 (8 waves).
// Fixes vs round 5 (counter-derived):
//  (1) VGPR_Count=56 proved the compiler sank the weight loads into the
//      K-loop (W_hh re-streamed 8192x -> the 83-149 GB FETCH_SIZE).
//      Now: float wreg[128] loaded once via float4, then 128 SCALAR
//      asm escapes ("+v" on one float each -- multi-reg tied constraints
//      don't compile on gfx950) pin them in VGPRs.
//  (2) LDS-broadcast matvec was ~3000cy/step (256 ds_read_b128/step,
//      CU-serialized). Now: SGPR-broadcast -- each lane reads 2 h floats,
//      then 128 x (v_readlane + v_fmac with SGPR operand). Zero LDS
//      traffic in the dot product.
// Transport unchanged (proven rounds 2/5): sentinel-poisoned h_hist words,
// relaxed agent-scope stores/polls, each word written exactly once.
// Roles after B1: wave 0 produce; waves 1-3 poll remote slices;
//                 waves 4-7 prefetch xw[t+1].
// ---------------------------------------------------------------------------
__global__ __launch_bounds__(512) void k_lstm(
    const float* __restrict__ whh_f, const float* __restrict__ whh_b,
    const float* __restrict__ h0, const float* __restrict__ c0,
    const float* __restrict__ xw, float* __restrict__ h_hist)
{
    const int role = blockIdx.x;     // 0..7, deterministic
    const int dir = role >> 2, w = role & 3;
    const float* __restrict__ whh = dir ? whh_b : whh_f;
    const int tid = threadIdx.x;
    const int q2 = tid >> 8;         // k-half 0..1 (uniform per wave)
    const int r = tid & 255;         // local gate-row (= g*64 + jj)
    const int R = (r >> 6) * 256 + w * 64 + (r & 63);   // global gate-row

    __shared__ float h_lds[256];
    __shared__ float partial[512];
    __shared__ float xw_lds[2][256];

    // 128 weights/thread, register-resident, pinned via scalar asm escapes.
    float wreg[128];
    {
        const float4* wp = (const float4*)&whh[(size_t)R * HD + q2 * 128];
#pragma unroll
        for (int u = 0; u < 32; ++u) {
            float4 v = wp[u];
            wreg[u * 4 + 0] = v.x;
            wreg[u * 4 + 1] = v.y;
            wreg[u * 4 + 2] = v.z;
            wreg[u * 4 + 3] = v.w;
        }
    }
#pragma unroll
    for (int u = 0; u < 128; ++u)
        asm volatile("" : "+v"(wreg[u]));   // single-VGPR tie: legal + pins

    if (tid < 256) {
        h_lds[tid] = h0[dir * HD + tid];
        xw_lds[0][tid] = xw[((size_t)dir * T_LEN) * G4
                            + (tid >> 6) * 256 + w * 64 + (tid & 63)];
    }

    const int wave = tid >> 6;
    const int lane = tid & 63;
    float c = 0.f;
    if (wave == 0) c = c0[dir * HD + w * 64 + lane];

    int ps = 0;                      // remote slice polled by waves 1-3
    if (wave >= 1 && wave <= 3) ps = (wave - 1) + ((wave - 1) >= w ? 1 : 0);

    __syncthreads();

    float* __restrict__ hh = h_hist + (size_t)dir * T_LEN * HD;

    for (int t = 0; t < T_LEN; ++t) {
        const int cur = t & 1, nxt = cur ^ 1;

        // SGPR-broadcast matvec over this thread's k-half.
        // Lane l holds h[q2*128 + l] and h[q2*128 + 64 + l]; readlane
        // broadcasts each to the whole wave through an SGPR.
        float h_v0 = h_lds[q2 * 128 + lane];
        float h_v1 = h_lds[q2 * 128 + 64 + lane];
        float ac0 = 0.f, ac1 = 0.f, ac2 = 0.f, ac3 = 0.f;
#pragma unroll
        for (int u = 0; u < 64; u += 4) {
            ac0 += wreg[u + 0] * __uint_as_float(
                __builtin_amdgcn_readlane(__float_as_uint(h_v0), u + 0));
            ac1 += wreg[u + 1] * __uint_as_float(
                __builtin_amdgcn_readlane(__float_as_uint(h_v0), u + 1));
            ac2 += wreg[u + 2] * __uint_as_float(
                __builtin_amdgcn_readlane(__float_as_uint(h_v0), u + 2));
            ac3 += wreg[u + 3] * __uint_as_float(
                __builtin_amdgcn_readlane(__float_as_uint(h_v0), u + 3));
        }
#pragma unroll
        for (int u = 0; u < 64; u += 4) {
            ac0 += wreg[64 + u + 0] * __uint_as_float(
                __builtin_amdgcn_readlane(__float_as_uint(h_v1), u + 0));
            ac1 += wreg[64 + u + 1] * __uint_as_float(
                __builtin_amdgcn_readlane(__float_as_uint(h_v1), u + 1));
            ac2 += wreg[64 + u + 2] * __uint_as_float(
                __builtin_amdgcn_readlane(__float_as_uint(h_v1), u + 2));
            ac3 += wreg[64 + u + 3] * __uint_as_float(
                __builtin_amdgcn_readlane(__float_as_uint(h_v1), u + 3));
        }
        partial[tid] = (ac0 + ac1) + (ac2 + ac3);   // partial[q2*256 + r]
        __syncthreads();   // B1

        if (wave == 0) {
            const int j = lane;
            float zi = xw_lds[cur][0 * 64 + j]
                     + partial[0 * 64 + j] + partial[256 + 0 * 64 + j];
            float zf = xw_lds[cur][1 * 64 + j]
                     + partial[1 * 64 + j] + partial[256 + 1 * 64 + j];
            float zg = xw_lds[cur][2 * 64 + j]
                     + partial[2 * 64 + j] + partial[256 + 2 * 64 + j];
            float zo = xw_lds[cur][3 * 64 + j]
                     + partial[3 * 64 + j] + partial[256 + 3 * 64 + j];
            float iv = 1.f / (1.f + expf(-zi));
            float fv = 1.f / (1.f + expf(-zf));
            float gv = tanhf(zg);
            float ov = 1.f / (1.f + expf(-zo));
            c = fv * c + iv * gv;
            float hv = ov * tanhf(c);
            h_lds[w * 64 + j] = hv;
            __hip_atomic_store((unsigned*)&hh[(size_t)t * HD + w * 64 + j],
                               __float_as_uint(hv),
                               __ATOMIC_RELAXED, __HIP_MEMORY_SCOPE_AGENT);
        } else if (wave <= 3) {
            const unsigned* src =
                (const unsigned*)&hh[(size_t)t * HD + ps * 64 + lane];
            unsigned v; int spin = 0;
            do {
                v = __hip_atomic_load(src, __ATOMIC_RELAXED,
                                      __HIP_MEMORY_SCOPE_AGENT);
            } while (v == 0xFFFFFFFFu && ++spin < (1 << 16));  // safety cap
            h_lds[ps * 64 + lane] = __uint_as_float(v);
        } else {
            const int i = (wave - 4) * 64 + lane;
            if (t + 1 < T_LEN)
                xw_lds[nxt][i] = xw[((size_t)dir * T_LEN + (t + 1)) * G4
                                    + (i >> 6) * 256 + w * 64 + (i & 63)];
        }
        __syncthreads();   // B2
    }
}

// ---------------------------------------------------------------------------
// Phase C: feats. One thread per t computes all 16 tags; W_out staged in
// LDS -> h_hist read exactly once. grid 32, block 256.
// ---------------------------------------------------------------------------
__global__ __launch_bounds__(256) void k_feats(
    const float* __restrict__ h_hist, const float* __restrict__ Wout,
    const float* __restrict__ bout, float* __restrict__ feats)
{
    __shared__ float wlds[16][512];
    const int tid = threadIdx.x;
    for (int i = tid; i < 16 * 512; i += 256) wlds[i >> 9][i & 511] = Wout[i];
    __syncthreads();
    const int t = blockIdx.x * 256 + tid;
    const float4* hf = (const float4*)(h_hist + (size_t)t * HD);
    const float4* hb = (const float4*)(h_hist + (size_t)(T_LEN + (T_LEN - 1 - t)) * HD);
    float acc[16];
#pragma unroll
    for (int g = 0; g < 16; ++g) acc[g] = bout[g];
    for (int k = 0; k < 64; ++k) {
        float4 a = hf[k];
#pragma unroll
        for (int g = 0; g < 16; ++g) {
            float4 b = *(const float4*)&wlds[g][k * 4];
            acc[g] += a.x * b.x + a.y * b.y + a.z * b.z + a.w * b.w;
        }
    }
    for (int k = 0; k < 64; ++k) {
        float4 a = hb[k];
#pragma unroll
        for (int g = 0; g < 16; ++g) {
            float4 b = *(const float4*)&wlds[g][256 + k * 4];
            acc[g] += a.x * b.x + a.y * b.y + a.z * b.z + a.w * b.w;
        }
    }
#pragma unroll
    for (int g = 0; g < 16; ++g) feats[(size_t)t * NT + g] = acc[g];
}

// ---------------------------------------------------------------------------
// Phase D: Viterbi (proven bit-exact path).
// ---------------------------------------------------------------------------
__device__ __forceinline__ unsigned bsel16(uint4 g, unsigned e) {
    unsigned wd = (e < 8u) ? ((e < 4u) ? g.x : g.y) : ((e < 12u) ? g.z : g.w);
    return (wd >> ((e & 3u) * 8u)) & 15u;
}

__global__ __launch_bounds__(256) void k_viterbi(
    const float* __restrict__ feats, const float* __restrict__ trans,
    int* __restrict__ out, unsigned char* __restrict__ bp)
{
    __shared__ int sid;
    __shared__ unsigned slo[512], shi[512];
    const int tid = threadIdx.x;

    if (tid < 64) {
        const int i = tid & 15, jg = tid >> 4;
        double tr[4];
#pragma unroll
        for (int u = 0; u < 4; ++u) tr[u] = (double)trans[i * 16 + jg * 4 + u];
        double fvn = (i == START_IX) ? 0.0 : -10000.0;
        float fA = feats[i];
        float fB = feats[16 + i];

        for (int t = 0; t < T_LEN; ++t) {
            float fC = (t + 2 < T_LEN) ? feats[(size_t)(t + 2) * NT + i] : 0.f;

            double best = -1e300; int bj = 0;
#pragma unroll
            for (int u = 0; u < 4; ++u) {
                double fvv = __shfl(fvn, jg * 4 + u);
                double v = fvv + tr[u];
                if (v > best) { best = v; bj = jg * 4 + u; }   // first-max
            }
            double ob = __shfl_down(best, 32); int oj = __shfl_down(bj, 32);
            if (ob > best || (ob == best && oj < bj)) { best = ob; bj = oj; }
            ob = __shfl_down(best, 16); oj = __shfl_down(bj, 16);
            if (ob > best || (ob == best && oj < bj)) { best = ob; bj = oj; }

            if (tid < 16) {
                bp[(size_t)t * 16 + i] = (unsigned char)bj;
                fvn = (double)fA + best;
            }
            fA = fB; fB = fC;
        }
        double term = (tid < 16) ? fvn + (double)trans[tid * 16 + STOP_IX] : -1e300;
        int ti = tid;
#pragma unroll
        for (int off = 1; off < 16; off <<= 1) {
            double ov = __shfl_xor(term, off); int oi = __shfl_xor(ti, off);
            if (ov > term || (ov == term && oi < ti)) { term = ov; ti = oi; }
        }
        if (tid == 0) sid = ti;
    }
    __syncthreads();

    const int j = tid;
    unsigned Flo = 0x76543210u, Fhi = 0xfedcba98u;
    for (int t = 32 * j + 31; t >= 32 * j; --t) {
        uint4 g = *(const uint4*)&bp[(size_t)t * 16];
        unsigned nlo = 0, nhi = 0;
#pragma unroll
        for (int x = 0; x < 8; ++x) {
            unsigned e = (Flo >> (x * 4)) & 15u;
            nlo |= bsel16(g, e) << (x * 4);
        }
#pragma unroll
        for (int x = 0; x < 8; ++x) {
            unsigned e = (Fhi >> (x * 4)) & 15u;
            nhi |= bsel16(g, e) << (x * 4);
        }
        Flo = nlo; Fhi = nhi;
    }
    slo[j] = Flo; shi[j] = Fhi;
    slo[j + 256] = 0x76543210u; shi[j + 256] = 0xfedcba98u;
    __syncthreads();
    for (int off = 1; off < 256; off <<= 1) {
        unsigned alo = slo[j], ahi = shi[j];
        unsigned blo = slo[j + off], bhi = shi[j + off];
        __syncthreads();
        unsigned nlo = 0, nhi = 0;
#pragma unroll
        for (int x = 0; x < 8; ++x) {
            unsigned e = (blo >> (x * 4)) & 15u;
            unsigned rr = ((e < 8u ? alo : ahi) >> ((e & 7u) * 4u)) & 15u;
            nlo |= rr << (x * 4);
        }
#pragma unroll
        for (int x = 0; x < 8; ++x) {
            unsigned e = (bhi >> (x * 4)) & 15u;
            unsigned rr = ((e < 8u ? alo : ahi) >> ((e & 7u) * 4u)) & 15u;
            nhi |= rr << (x * 4);
        }
        slo[j] = nlo; shi[j] = nhi;
        __syncthreads();
    }
    int idl = sid;
    unsigned plo = slo[j + 1], phi = shi[j + 1];
    unsigned x = (((unsigned)idl < 8u ? plo : phi) >> (((unsigned)idl & 7u) * 4u)) & 15u;
    out[32 * j + 31] = (int)x;
    for (int t = 32 * j + 30; t >= 32 * j; --t) {
        x = (unsigned)bp[(size_t)(t + 1) * 16 + x];
        out[t] = (int)x;
    }
}

// ---------------------------------------------------------------------------
extern "C" void kernel_launch(void* const* d_in, const int* in_sizes, int n_in,
                              void* d_out, int out_size, void* d_ws, size_t ws_size,
                              hipStream_t stream) {
    const int*   sent  = (const int*)  d_in[0];
    const float* embed = (const float*)d_in[1];
    const float* wih_f = (const float*)d_in[2];
    const float* whh_f = (const float*)d_in[3];
    const float* bih_f = (const float*)d_in[4];
    const float* bhh_f = (const float*)d_in[5];
    const float* wih_b = (const float*)d_in[6];
    const float* whh_b = (const float*)d_in[7];
    const float* bih_b = (const float*)d_in[8];
    const float* bhh_b = (const float*)d_in[9];
    const float* Wout  = (const float*)d_in[10];
    const float* bout  = (const float*)d_in[11];
    const float* trans = (const float*)d_in[12];
    const float* h0    = (const float*)d_in[13];
    const float* c0    = (const float*)d_in[14];
    int* out = (int*)d_out;

    float* ws_xw   = (float*)d_ws;                                  // 2*T*1024 f
    float* ws_h    = ws_xw + (size_t)2 * T_LEN * G4;                // 2*T*256 f
    float* ws_feat = ws_h + (size_t)2 * T_LEN * HD;                 // T*16 f
    unsigned char* ws_bp = (unsigned char*)(ws_feat + (size_t)T_LEN * NT); // T*16 B

    // sentinel-fill h_hist every launch: 0xFFFFFFFF (-NaN) is unreachable
    // from finite arithmetic; each word is then written exactly once.
    hipMemsetAsync(ws_h, 0xFF, (size_t)2 * T_LEN * HD * sizeof(float), stream);

    dim3 gA(T_LEN / 32, G4 / 128, 2);
    k_gemm_xw<<<gA, 256, 0, stream>>>(sent, embed, wih_f, wih_b,
                                      bih_f, bhh_f, bih_b, bhh_b, ws_xw);
    k_lstm<<<8, 512, 0, stream>>>(whh_f, whh_b, h0, c0, ws_xw, ws_h);
    k_feats<<<32, 256, 0, stream>>>(ws_h, Wout, bout, ws_feat);
    k_viterbi<<<1, 256, 0, stream>>>(ws_feat, trans, out, ws_bp);
}

// Round 8
// 17004.878 us; speedup vs baseline: 1.2039x; 1.1454x over previous
//
#include <hip/hip_runtime.h>
#include <cstdint>
#include <cstddef>

#define T_LEN 8192
#define EMB 256
#define HD 256          // hidden per direction
#define G4 1024         // 4*HD
#define NT 16
#define START_IX 14
#define STOP_IX 15

#define NWG_DIR 16      // WGs per direction
#define SLICE 16        // h outputs per WG
#define ROWS 64         // gate rows per WG (4 gates x 16)
#define WPAD 257        // 257 % 32 == 1 -> adjacent rows land in adjacent banks

// ---------------------------------------------------------------------------
// Phase A: xw[dir][t][r] = emb[dir? T-1-t : t] @ w_ih^T + (b_ih + b_hh)
// grid (T/32, G4/128, 2), block 256   (proven)
// ---------------------------------------------------------------------------
__global__ __launch_bounds__(256) void k_gemm_xw(
    const int* __restrict__ sent, const float* __restrict__ embed,
    const float* __restrict__ wih_f, const float* __restrict__ wih_b,
    const float* __restrict__ bih_f, const float* __restrict__ bhh_f,
    const float* __restrict__ bih_b, const float* __restrict__ bhh_b,
    float* __restrict__ xw)
{
    const int dir = blockIdx.z;
    const float* __restrict__ wih = dir ? wih_b : wih_f;
    const float* __restrict__ bih = dir ? bih_b : bih_f;
    const float* __restrict__ bhh = dir ? bhh_b : bhh_f;
    __shared__ float at[32][65];
    __shared__ float bt[128][65];
    const int t0 = blockIdx.x * 32, r0 = blockIdx.y * 128;
    const int tid = threadIdx.x;
    const int tx = tid & 31, ty = tid >> 5;
    float acc[4][4] = {};
    for (int k0 = 0; k0 < EMB; k0 += 64) {
        for (int i = tid; i < 32 * 64; i += 256) {
            int row = i >> 6, k = i & 63;
            int t = t0 + row;
            int ts = dir ? (T_LEN - 1 - t) : t;
            at[row][k] = embed[(size_t)sent[ts] * EMB + k0 + k];
        }
        for (int i = tid; i < 128 * 64; i += 256) {
            int row = i >> 6, k = i & 63;
            bt[row][k] = wih[(size_t)(r0 + row) * EMB + k0 + k];
        }
        __syncthreads();
#pragma unroll 16
        for (int kc = 0; kc < 64; ++kc) {
            float a[4], b[4];
#pragma unroll
            for (int u = 0; u < 4; ++u) a[u] = at[ty * 4 + u][kc];
#pragma unroll
            for (int u = 0; u < 4; ++u) b[u] = bt[tx * 4 + u][kc];
#pragma unroll
            for (int u = 0; u < 4; ++u)
#pragma unroll
                for (int v = 0; v < 4; ++v) acc[u][v] += a[u] * b[v];
        }
        __syncthreads();
    }
#pragma unroll
    for (int u = 0; u < 4; ++u) {
        int t = t0 + ty * 4 + u;
#pragma unroll
        for (int v = 0; v < 4; ++v) {
            int r = r0 + tx * 4 + v;
            xw[((size_t)dir * T_LEN + t) * G4 + r] = acc[u][v] + bih[r] + bhh[r];
        }
    }
}

// ---------------------------------------------------------------------------
// Phase B: LSTM scans. grid 32 (= dir*16 + wsl), block 512 (8 waves).
// Design derived from r5/r7 counters (see session journal):
//  * Weights LDS-RESIDENT (64 KB/WG, staged once) -> kills the 83 GB/step
//    W_hh re-stream that VGPR pinning failed to kill twice (VGPR=56/80).
//    WPAD=257 (== 1 mod 32) -> weight reads are 2-way bank aliases (free).
//  * Matvec: thread (seg=wave, row=lane) does 32 k of one gate-row:
//    32 scalar LDS w-reads + 8 b128 h broadcasts + 32 FMA. LDS-BW floor
//    ~640 cy/step/CU.
//  * Produce: single wave; z = xw + 8 partials; act; gate gather via 3
//    __shfl; c/h update on lanes 0-15; 16-float slice = ONE 64B line
//    stored with relaxed agent atomics.
//  * Polls: spaced sampling (s_sleep between samples) -> detection
//    granularity ~128 cy instead of ~900 cy dependent-load chain.
// Transport (proven r2/r5): h_hist words sentinel-poisoned per launch,
// written exactly once, polled directly. No flags, no parity, no ABA.
// ---------------------------------------------------------------------------
__global__ __launch_bounds__(512) void k_lstm(
    const float* __restrict__ whh_f, const float* __restrict__ whh_b,
    const float* __restrict__ h0, const float* __restrict__ c0,
    const float* __restrict__ xw, float* __restrict__ h_hist)
{
    const int role = blockIdx.x;          // 0..31, deterministic
    const int dir = role >> 4, wsl = role & 15;
    const float* __restrict__ whh = dir ? whh_b : whh_f;
    const int tid = threadIdx.x;
    const int wave = tid >> 6, lane = tid & 63;

    __shared__ float wlds[ROWS * WPAD];   // 64.25 KB
    __shared__ float h_lds[256];
    __shared__ float partial[8 * 64];
    __shared__ float xw_lds[2][64];

    // stage weights once: local row r -> global gate-row R
    for (int i = tid; i < ROWS * 256; i += 512) {
        int r = i >> 8, k = i & 255;
        int R = ((r >> 4) << 8) + wsl * SLICE + (r & 15);
        wlds[r * WPAD + k] = whh[(size_t)R * HD + k];
    }
    if (tid < 256) h_lds[tid] = h0[dir * HD + tid];
    if (tid < 64) {
        int R = ((tid >> 4) << 8) + wsl * SLICE + (tid & 15);
        xw_lds[0][tid] = xw[((size_t)dir * T_LEN) * G4 + R];
    }
    float c = 0.f;
    if (wave == 0 && lane < 16) c = c0[dir * HD + wsl * SLICE + lane];
    __syncthreads();

    float* __restrict__ hh = h_hist + (size_t)dir * T_LEN * HD;

    for (int t = 0; t < T_LEN; ++t) {
        const int cur = t & 1, nxt = cur ^ 1;

        // ---- matvec partial: row=lane, k-segment=wave (32 k) ----
        {
            const float* wr = &wlds[lane * WPAD + wave * 32];
            const float* hp = &h_lds[wave * 32];
            float a0 = 0.f, a1 = 0.f, a2 = 0.f, a3 = 0.f;
#pragma unroll
            for (int i = 0; i < 8; ++i) {
                float4 hv = *(const float4*)&hp[i * 4];   // wave-uniform b128
                a0 += wr[i * 4 + 0] * hv.x;
                a1 += wr[i * 4 + 1] * hv.y;
                a2 += wr[i * 4 + 2] * hv.z;
                a3 += wr[i * 4 + 3] * hv.w;
            }
            partial[wave * 64 + lane] = (a0 + a1) + (a2 + a3);
        }
        __syncthreads();   // B1

        if (wave == 0) {
            // lane = gate-row (g = lane>>4, j = lane&15)
            float z = xw_lds[cur][lane];
#pragma unroll
            for (int s = 0; s < 8; ++s) z += partial[s * 64 + lane];
            float a = ((lane >> 4) == 2) ? tanhf(z) : 1.f / (1.f + expf(-z));
            const int jm = lane & 15;
            float fg = __shfl(a, 16 + jm);
            float gg = __shfl(a, 32 + jm);
            float og = __shfl(a, 48 + jm);
            if (lane < 16) {
                c = fg * c + a * gg;
                float hv = og * tanhf(c);
                h_lds[wsl * SLICE + lane] = hv;
                __hip_atomic_store(
                    (unsigned*)&hh[(size_t)t * HD + wsl * SLICE + lane],
                    __float_as_uint(hv),
                    __ATOMIC_RELAXED, __HIP_MEMORY_SCOPE_AGENT);
            }
        } else if (wave <= 4) {
            // poll remote slices: idx covers all (s,j); own slice skipped
            const int idx = (wave - 1) * 64 + lane;   // 0..255
            const int s = idx >> 4, j = idx & 15;
            if (s != wsl) {
                const unsigned* src =
                    (const unsigned*)&hh[(size_t)t * HD + s * SLICE + j];
                unsigned v = __hip_atomic_load(src, __ATOMIC_RELAXED,
                                               __HIP_MEMORY_SCOPE_AGENT);
                int spin = 0;
                while (v == 0xFFFFFFFFu && ++spin < (1 << 16)) {
                    __builtin_amdgcn_s_sleep(1);      // space the samples
                    v = __hip_atomic_load(src, __ATOMIC_RELAXED,
                                          __HIP_MEMORY_SCOPE_AGENT);
                }
                h_lds[s * SLICE + j] = __uint_as_float(v);
            }
        } else if (wave == 5) {
            if (t + 1 < T_LEN) {
                int R = ((lane >> 4) << 8) + wsl * SLICE + (lane & 15);
                xw_lds[nxt][lane] =
                    xw[((size_t)dir * T_LEN + (t + 1)) * G4 + R];
            }
        }
        __syncthreads();   // B2
    }
}

// ---------------------------------------------------------------------------
// Phase C: feats. One thread per t computes all 16 tags; W_out staged in
// LDS -> h_hist read exactly once. grid 32, block 256.
// ---------------------------------------------------------------------------
__global__ __launch_bounds__(256) void k_feats(
    const float* __restrict__ h_hist, const float* __restrict__ Wout,
    const float* __restrict__ bout, float* __restrict__ feats)
{
    __shared__ float wlds[16][512];
    const int tid = threadIdx.x;
    for (int i = tid; i < 16 * 512; i += 256) wlds[i >> 9][i & 511] = Wout[i];
    __syncthreads();
    const int t = blockIdx.x * 256 + tid;
    const float4* hf = (const float4*)(h_hist + (size_t)t * HD);
    const float4* hb = (const float4*)(h_hist + (size_t)(T_LEN + (T_LEN - 1 - t)) * HD);
    float acc[16];
#pragma unroll
    for (int g = 0; g < 16; ++g) acc[g] = bout[g];
    for (int k = 0; k < 64; ++k) {
        float4 a = hf[k];
#pragma unroll
        for (int g = 0; g < 16; ++g) {
            float4 b = *(const float4*)&wlds[g][k * 4];
            acc[g] += a.x * b.x + a.y * b.y + a.z * b.z + a.w * b.w;
        }
    }
    for (int k = 0; k < 64; ++k) {
        float4 a = hb[k];
#pragma unroll
        for (int g = 0; g < 16; ++g) {
            float4 b = *(const float4*)&wlds[g][256 + k * 4];
            acc[g] += a.x * b.x + a.y * b.y + a.z * b.z + a.w * b.w;
        }
    }
#pragma unroll
    for (int g = 0; g < 16; ++g) feats[(size_t)t * NT + g] = acc[g];
}

// ---------------------------------------------------------------------------
// Phase D: Viterbi (proven bit-exact path).
// ---------------------------------------------------------------------------
__device__ __forceinline__ unsigned bsel16(uint4 g, unsigned e) {
    unsigned wd = (e < 8u) ? ((e < 4u) ? g.x : g.y) : ((e < 12u) ? g.z : g.w);
    return (wd >> ((e & 3u) * 8u)) & 15u;
}

__global__ __launch_bounds__(256) void k_viterbi(
    const float* __restrict__ feats, const float* __restrict__ trans,
    int* __restrict__ out, unsigned char* __restrict__ bp)
{
    __shared__ int sid;
    __shared__ unsigned slo[512], shi[512];
    const int tid = threadIdx.x;

    if (tid < 64) {
        const int i = tid & 15, jg = tid >> 4;
        double tr[4];
#pragma unroll
        for (int u = 0; u < 4; ++u) tr[u] = (double)trans[i * 16 + jg * 4 + u];
        double fvn = (i == START_IX) ? 0.0 : -10000.0;
        float fA = feats[i];
        float fB = feats[16 + i];

        for (int t = 0; t < T_LEN; ++t) {
            float fC = (t + 2 < T_LEN) ? feats[(size_t)(t + 2) * NT + i] : 0.f;

            double best = -1e300; int bj = 0;
#pragma unroll
            for (int u = 0; u < 4; ++u) {
                double fvv = __shfl(fvn, jg * 4 + u);
                double v = fvv + tr[u];
                if (v > best) { best = v; bj = jg * 4 + u; }   // first-max
            }
            double ob = __shfl_down(best, 32); int oj = __shfl_down(bj, 32);
            if (ob > best || (ob == best && oj < bj)) { best = ob; bj = oj; }
            ob = __shfl_down(best, 16); oj = __shfl_down(bj, 16);
            if (ob > best || (ob == best && oj < bj)) { best = ob; bj = oj; }

            if (tid < 16) {
                bp[(size_t)t * 16 + i] = (unsigned char)bj;
                fvn = (double)fA + best;
            }
            fA = fB; fB = fC;
        }
        double term = (tid < 16) ? fvn + (double)trans[tid * 16 + STOP_IX] : -1e300;
        int ti = tid;
#pragma unroll
        for (int off = 1; off < 16; off <<= 1) {
            double ov = __shfl_xor(term, off); int oi = __shfl_xor(ti, off);
            if (ov > term || (ov == term && oi < ti)) { term = ov; ti = oi; }
        }
        if (tid == 0) sid = ti;
    }
    __syncthreads();

    const int j = tid;
    unsigned Flo = 0x76543210u, Fhi = 0xfedcba98u;
    for (int t = 32 * j + 31; t >= 32 * j; --t) {
        uint4 g = *(const uint4*)&bp[(size_t)t * 16];
        unsigned nlo = 0, nhi = 0;
#pragma unroll
        for (int x = 0; x < 8; ++x) {
            unsigned e = (Flo >> (x * 4)) & 15u;
            nlo |= bsel16(g, e) << (x * 4);
        }
#pragma unroll
        for (int x = 0; x < 8; ++x) {
            unsigned e = (Fhi >> (x * 4)) & 15u;
            nhi |= bsel16(g, e) << (x * 4);
        }
        Flo = nlo; Fhi = nhi;
    }
    slo[j] = Flo; shi[j] = Fhi;
    slo[j + 256] = 0x76543210u; shi[j + 256] = 0xfedcba98u;
    __syncthreads();
    for (int off = 1; off < 256; off <<= 1) {
        unsigned alo = slo[j], ahi = shi[j];
        unsigned blo = slo[j + off], bhi = shi[j + off];
        __syncthreads();
        unsigned nlo = 0, nhi = 0;
#pragma unroll
        for (int x = 0; x < 8; ++x) {
            unsigned e = (blo >> (x * 4)) & 15u;
            unsigned rr = ((e < 8u ? alo : ahi) >> ((e & 7u) * 4u)) & 15u;
            nlo |= rr << (x * 4);
        }
#pragma unroll
        for (int x = 0; x < 8; ++x) {
            unsigned e = (bhi >> (x * 4)) & 15u;
            unsigned rr = ((e < 8u ? alo : ahi) >> ((e & 7u) * 4u)) & 15u;
            nhi |= rr << (x * 4);
        }
        slo[j] = nlo; shi[j] = nhi;
        __syncthreads();
    }
    int idl = sid;
    unsigned plo = slo[j + 1], phi = shi[j + 1];
    unsigned x = (((unsigned)idl < 8u ? plo : phi) >> (((unsigned)idl & 7u) * 4u)) & 15u;
    out[32 * j + 31] = (int)x;
    for (int t = 32 * j + 30; t >= 32 * j; --t) {
        x = (unsigned)bp[(size_t)(t + 1) * 16 + x];
        out[t] = (int)x;
    }
}

// ---------------------------------------------------------------------------
extern "C" void kernel_launch(void* const* d_in, const int* in_sizes, int n_in,
                              void* d_out, int out_size, void* d_ws, size_t ws_size,
                              hipStream_t stream) {
    const int*   sent  = (const int*)  d_in[0];
    const float* embed = (const float*)d_in[1];
    const float* wih_f = (const float*)d_in[2];
    const float* whh_f = (const float*)d_in[3];
    const float* bih_f = (const float*)d_in[4];
    const float* bhh_f = (const float*)d_in[5];
    const float* wih_b = (const float*)d_in[6];
    const float* whh_b = (const float*)d_in[7];
    const float* bih_b = (const float*)d_in[8];
    const float* bhh_b = (const float*)d_in[9];
    const float* Wout  = (const float*)d_in[10];
    const float* bout  = (const float*)d_in[11];
    const float* trans = (const float*)d_in[12];
    const float* h0    = (const float*)d_in[13];
    const float* c0    = (const float*)d_in[14];
    int* out = (int*)d_out;

    float* ws_xw   = (float*)d_ws;                                  // 2*T*1024 f
    float* ws_h    = ws_xw + (size_t)2 * T_LEN * G4;                // 2*T*256 f
    float* ws_feat = ws_h + (size_t)2 * T_LEN * HD;                 // T*16 f
    unsigned char* ws_bp = (unsigned char*)(ws_feat + (size_t)T_LEN * NT); // T*16 B

    // sentinel-fill h_hist every launch: 0xFFFFFFFF (-NaN) is unreachable
    // from finite arithmetic; each word is then written exactly once.
    hipMemsetAsync(ws_h, 0xFF, (size_t)2 * T_LEN * HD * sizeof(float), stream);

    dim3 gA(T_LEN / 32, G4 / 128, 2);
    k_gemm_xw<<<gA, 256, 0, stream>>>(sent, embed, wih_f, wih_b,
                                      bih_f, bhh_f, bih_b, bhh_b, ws_xw);
    k_lstm<<<32, 512, 0, stream>>>(whh_f, whh_b, h0, c0, ws_xw, ws_h);
    k_feats<<<32, 256, 0, stream>>>(ws_h, Wout, bout, ws_feat);
    k_viterbi<<<1, 256, 0, stream>>>(ws_feat, trans, out, ws_bp);
}

// Round 9
// 16683.730 us; speedup vs baseline: 1.2270x; 1.0192x over previous
//
#include <hip/hip_runtime.h>
#include <cstdint>
#include <cstddef>

#define T_LEN 8192
#define EMB 256
#define HD 256          // hidden per direction
#define G4 1024         // 4*HD
#define NT 16
#define START_IX 14
#define STOP_IX 15

#define NWG_DIR 16      // WGs per direction
#define SLICE 16        // h outputs per WG
#define ROWS 64         // gate rows per WG (4 gates x 16)
#define WPAD 260        // 260*4=1040B: 16B-aligned rows (b128 legal), stride==4 mod 32
                        // banks -> each b128 wave-instr hits all 32 banks 8-deep
                        // (balanced) ~= conflict-free BW floor
#define SENT 0xFFFFFFFFu

// ---------------------------------------------------------------------------
// Phase A: xw[dir][t][r] = emb[dir? T-1-t : t] @ w_ih^T + (b_ih + b_hh)
// grid (T/32, G4/128, 2), block 256   (proven)
// ---------------------------------------------------------------------------
__global__ __launch_bounds__(256) void k_gemm_xw(
    const int* __restrict__ sent, const float* __restrict__ embed,
    const float* __restrict__ wih_f, const float* __restrict__ wih_b,
    const float* __restrict__ bih_f, const float* __restrict__ bhh_f,
    const float* __restrict__ bih_b, const float* __restrict__ bhh_b,
    float* __restrict__ xw)
{
    const int dir = blockIdx.z;
    const float* __restrict__ wih = dir ? wih_b : wih_f;
    const float* __restrict__ bih = dir ? bih_b : bih_f;
    const float* __restrict__ bhh = dir ? bhh_b : bhh_f;
    __shared__ float at[32][65];
    __shared__ float bt[128][65];
    const int t0 = blockIdx.x * 32, r0 = blockIdx.y * 128;
    const int tid = threadIdx.x;
    const int tx = tid & 31, ty = tid >> 5;
    float acc[4][4] = {};
    for (int k0 = 0; k0 < EMB; k0 += 64) {
        for (int i = tid; i < 32 * 64; i += 256) {
            int row = i >> 6, k = i & 63;
            int t = t0 + row;
            int ts = dir ? (T_LEN - 1 - t) : t;
            at[row][k] = embed[(size_t)sent[ts] * EMB + k0 + k];
        }
        for (int i = tid; i < 128 * 64; i += 256) {
            int row = i >> 6, k = i & 63;
            bt[row][k] = wih[(size_t)(r0 + row) * EMB + k0 + k];
        }
        __syncthreads();
#pragma unroll 16
        for (int kc = 0; kc < 64; ++kc) {
            float a[4], b[4];
#pragma unroll
            for (int u = 0; u < 4; ++u) a[u] = at[ty * 4 + u][kc];
#pragma unroll
            for (int u = 0; u < 4; ++u) b[u] = bt[tx * 4 + u][kc];
#pragma unroll
            for (int u = 0; u < 4; ++u)
#pragma unroll
                for (int v = 0; v < 4; ++v) acc[u][v] += a[u] * b[v];
        }
        __syncthreads();
    }
#pragma unroll
    for (int u = 0; u < 4; ++u) {
        int t = t0 + ty * 4 + u;
#pragma unroll
        for (int v = 0; v < 4; ++v) {
            int r = r0 + tx * 4 + v;
            xw[((size_t)dir * T_LEN + t) * G4 + r] = acc[u][v] + bih[r] + bhh[r];
        }
    }
}

// ---------------------------------------------------------------------------
// Pipelined poll sampler. Depth-2 ping-pong of raw loads (sc0 sc1: most-
// bypassing cache combo -> serviced at/through MALL) spaced ~128cy, harvested
// with counted vmcnt(1) (semantics HW-verified per guide m135). Monotonic
// word (sentinel -> final, written once) => any non-sentinel sample is THE
// value; stale cached sentinels only delay, never corrupt. If the sc bits
// don't give MALL visibility, every sample misses and the PROVEN agent-scope
// atomic fallback loop below fires -> worst case == round-8 behavior.
// Stale in-flight loads at exit (<=1) only make later vmcnt waits stricter.
// ---------------------------------------------------------------------------
#define PP_ISSUE(x, p)                                                        \
    asm volatile("global_load_dword %0, %1, off sc0 sc1"                      \
                 : "=v"(x) : "v"(p) : "memory");                              \
    __builtin_amdgcn_sched_barrier(0)
#define PP_WAIT1()                                                            \
    asm volatile("s_waitcnt vmcnt(1)" ::: "memory");                          \
    __builtin_amdgcn_sched_barrier(0)
#define PP_SPACE() asm volatile("s_sleep 2" ::: "memory")

__device__ __forceinline__ unsigned poll_word(const unsigned* p) {
    unsigned v = __hip_atomic_load(p, __ATOMIC_RELAXED, __HIP_MEMORY_SCOPE_AGENT);
    if (__builtin_amdgcn_ballot_w64(v == SENT) != 0ull) {
        unsigned sA, sB;
        PP_ISSUE(sA, p);
        PP_SPACE();
#pragma unroll
        for (int it = 0; it < 6; ++it) {
            PP_ISSUE(sB, p);
            PP_WAIT1();                       // sA complete
            if (v == SENT) v = sA;
            if (__builtin_amdgcn_ballot_w64(v == SENT) == 0ull) break;
            PP_SPACE();
            PP_ISSUE(sA, p);
            PP_WAIT1();                       // sB complete
            if (v == SENT) v = sB;
            if (__builtin_amdgcn_ballot_w64(v == SENT) == 0ull) break;
            PP_SPACE();
        }
    }
    // proven fallback (rounds 2/5/7/8 transport)
    int spin = 0;
    while (__builtin_amdgcn_ballot_w64(v == SENT) != 0ull && ++spin < (1 << 16)) {
        asm volatile("s_sleep 1" ::: "memory");
        unsigned nv = __hip_atomic_load(p, __ATOMIC_RELAXED,
                                        __HIP_MEMORY_SCOPE_AGENT);
        if (v == SENT) v = nv;
    }
    return v;
}

// ---------------------------------------------------------------------------
// Phase B: LSTM scans. grid 32 (= dir*16 + wsl), block 512 (8 waves).
// vs round 8 (counter-derived):
//  * WPAD 257->260 + explicit float4 weight reads: 64 balanced ds_read_b128
//    per step instead of 256 ds_read_b32 -> matvec ~1500 -> ~900 cy.
//  * poll_word(): pipelined sampling (~130cy granularity) with proven
//    fallback -> detect lag ~900 -> ~300cy if sc0sc1 is MALL-visible.
// Transport invariants unchanged: h_hist sentinel-poisoned per launch,
// words written exactly once with relaxed agent atomics, polled directly.
// ---------------------------------------------------------------------------
__global__ __launch_bounds__(512) void k_lstm(
    const float* __restrict__ whh_f, const float* __restrict__ whh_b,
    const float* __restrict__ h0, const float* __restrict__ c0,
    const float* __restrict__ xw, float* __restrict__ h_hist)
{
    const int role = blockIdx.x;          // 0..31, deterministic
    const int dir = role >> 4, wsl = role & 15;
    const float* __restrict__ whh = dir ? whh_b : whh_f;
    const int tid = threadIdx.x;
    const int wave = tid >> 6, lane = tid & 63;

    __shared__ float wlds[ROWS * WPAD];   // 65 KB
    __shared__ float h_lds[256];
    __shared__ float partial[8 * 64];
    __shared__ float xw_lds[2][64];

    // stage weights once: local row r -> global gate-row R
    for (int i = tid; i < ROWS * 256; i += 512) {
        int r = i >> 8, k = i & 255;
        int R = ((r >> 4) << 8) + wsl * SLICE + (r & 15);
        wlds[r * WPAD + k] = whh[(size_t)R * HD + k];
    }
    if (tid < 256) h_lds[tid] = h0[dir * HD + tid];
    if (tid < 64) {
        int R = ((tid >> 4) << 8) + wsl * SLICE + (tid & 15);
        xw_lds[0][tid] = xw[((size_t)dir * T_LEN) * G4 + R];
    }
    float c = 0.f;
    if (wave == 0 && lane < 16) c = c0[dir * HD + wsl * SLICE + lane];
    __syncthreads();

    float* __restrict__ hh = h_hist + (size_t)dir * T_LEN * HD;

    for (int t = 0; t < T_LEN; ++t) {
        const int cur = t & 1, nxt = cur ^ 1;

        // ---- matvec partial: row=lane, k-segment=wave (32 k), b128 reads ----
        {
            const float4* wr = (const float4*)&wlds[lane * WPAD + wave * 32];
            const float4* hp = (const float4*)&h_lds[wave * 32];
            float a0 = 0.f, a1 = 0.f, a2 = 0.f, a3 = 0.f;
#pragma unroll
            for (int i = 0; i < 8; ++i) {
                float4 wv = wr[i];                 // balanced b128
                float4 hv = hp[i];                 // wave-uniform broadcast
                a0 += wv.x * hv.x;
                a1 += wv.y * hv.y;
                a2 += wv.z * hv.z;
                a3 += wv.w * hv.w;
            }
            partial[wave * 64 + lane] = (a0 + a1) + (a2 + a3);
        }
        __syncthreads();   // B1

        if (wave == 0) {
            // lane = gate-row (g = lane>>4, j = lane&15)
            float z = xw_lds[cur][lane];
#pragma unroll
            for (int s = 0; s < 8; ++s) z += partial[s * 64 + lane];
            float a = ((lane >> 4) == 2) ? tanhf(z) : 1.f / (1.f + expf(-z));
            const int jm = lane & 15;
            float fg = __shfl(a, 16 + jm);
            float gg = __shfl(a, 32 + jm);
            float og = __shfl(a, 48 + jm);
            if (lane < 16) {
                c = fg * c + a * gg;
                float hv = og * tanhf(c);
                h_lds[wsl * SLICE + lane] = hv;
                __hip_atomic_store(
                    (unsigned*)&hh[(size_t)t * HD + wsl * SLICE + lane],
                    __float_as_uint(hv),
                    __ATOMIC_RELAXED, __HIP_MEMORY_SCOPE_AGENT);
            }
        } else if (wave <= 4) {
            // poll remote slices; own slice produced locally
            const int idx = (wave - 1) * 64 + lane;   // 0..255
            const int s = idx >> 4, j = idx & 15;
            if (s != wsl) {
                unsigned v = poll_word(
                    (const unsigned*)&hh[(size_t)t * HD + s * SLICE + j]);
                h_lds[s * SLICE + j] = __uint_as_float(v);
            }
        } else if (wave == 5) {
            if (t + 1 < T_LEN) {
                int R = ((lane >> 4) << 8) + wsl * SLICE + (lane & 15);
                xw_lds[nxt][lane] =
                    xw[((size_t)dir * T_LEN + (t + 1)) * G4 + R];
            }
        }
        __syncthreads();   // B2
    }
}

// ---------------------------------------------------------------------------
// Phase C: feats. 4-way tag split (idx -> t = idx>>2, 4 tags each) so 128
// WGs keep >64 CUs busy (was 32 WGs / 8192 threads -> ~0.9ms). W_out staged
// in LDS; h_hist read once per 4-thread group. grid 128, block 256.
// ---------------------------------------------------------------------------
__global__ __launch_bounds__(256) void k_feats(
    const float* __restrict__ h_hist, const float* __restrict__ Wout,
    const float* __restrict__ bout, float* __restrict__ feats)
{
    __shared__ float wlds[16][512];
    const int tid = threadIdx.x;
    for (int i = tid; i < 16 * 512; i += 256) wlds[i >> 9][i & 511] = Wout[i];
    __syncthreads();
    const int idx = blockIdx.x * 256 + tid;          // 0..32767
    const int t = idx >> 2, tg = (idx & 3) * 4;      // 4 tags per thread
    const float4* hf = (const float4*)(h_hist + (size_t)t * HD);
    const float4* hb = (const float4*)(h_hist + (size_t)(T_LEN + (T_LEN - 1 - t)) * HD);
    float acc[4];
#pragma unroll
    for (int g = 0; g < 4; ++g) acc[g] = bout[tg + g];
    for (int k = 0; k < 64; ++k) {
        float4 a = hf[k];
#pragma unroll
        for (int g = 0; g < 4; ++g) {
            float4 b = *(const float4*)&wlds[tg + g][k * 4];
            acc[g] += a.x * b.x + a.y * b.y + a.z * b.z + a.w * b.w;
        }
    }
    for (int k = 0; k < 64; ++k) {
        float4 a = hb[k];
#pragma unroll
        for (int g = 0; g < 4; ++g) {
            float4 b = *(const float4*)&wlds[tg + g][256 + k * 4];
            acc[g] += a.x * b.x + a.y * b.y + a.z * b.z + a.w * b.w;
        }
    }
#pragma unroll
    for (int g = 0; g < 4; ++g) feats[(size_t)t * NT + tg + g] = acc[g];
}

// ---------------------------------------------------------------------------
// Phase D: Viterbi (proven bit-exact path).
// ---------------------------------------------------------------------------
__device__ __forceinline__ unsigned bsel16(uint4 g, unsigned e) {
    unsigned wd = (e < 8u) ? ((e < 4u) ? g.x : g.y) : ((e < 12u) ? g.z : g.w);
    return (wd >> ((e & 3u) * 8u)) & 15u;
}

__global__ __launch_bounds__(256) void k_viterbi(
    const float* __restrict__ feats, const float* __restrict__ trans,
    int* __restrict__ out, unsigned char* __restrict__ bp)
{
    __shared__ int sid;
    __shared__ unsigned slo[512], shi[512];
    const int tid = threadIdx.x;

    if (tid < 64) {
        const int i = tid & 15, jg = tid >> 4;
        double tr[4];
#pragma unroll
        for (int u = 0; u < 4; ++u) tr[u] = (double)trans[i * 16 + jg * 4 + u];
        double fvn = (i == START_IX) ? 0.0 : -10000.0;
        float fA = feats[i];
        float fB = feats[16 + i];

        for (int t = 0; t < T_LEN; ++t) {
            float fC = (t + 2 < T_LEN) ? feats[(size_t)(t + 2) * NT + i] : 0.f;

            double best = -1e300; int bj = 0;
#pragma unroll
            for (int u = 0; u < 4; ++u) {
                double fvv = __shfl(fvn, jg * 4 + u);
                double v = fvv + tr[u];
                if (v > best) { best = v; bj = jg * 4 + u; }   // first-max
            }
            double ob = __shfl_down(best, 32); int oj = __shfl_down(bj, 32);
            if (ob > best || (ob == best && oj < bj)) { best = ob; bj = oj; }
            ob = __shfl_down(best, 16); oj = __shfl_down(bj, 16);
            if (ob > best || (ob == best && oj < bj)) { best = ob; bj = oj; }

            if (tid < 16) {
                bp[(size_t)t * 16 + i] = (unsigned char)bj;
                fvn = (double)fA + best;
            }
            fA = fB; fB = fC;
        }
        double term = (tid < 16) ? fvn + (double)trans[tid * 16 + STOP_IX] : -1e300;
        int ti = tid;
#pragma unroll
        for (int off = 1; off < 16; off <<= 1) {
            double ov = __shfl_xor(term, off); int oi = __shfl_xor(ti, off);
            if (ov > term || (ov == term && oi < ti)) { term = ov; ti = oi; }
        }
        if (tid == 0) sid = ti;
    }
    __syncthreads();

    const int j = tid;
    unsigned Flo = 0x76543210u, Fhi = 0xfedcba98u;
    for (int t = 32 * j + 31; t >= 32 * j; --t) {
        uint4 g = *(const uint4*)&bp[(size_t)t * 16];
        unsigned nlo = 0, nhi = 0;
#pragma unroll
        for (int x = 0; x < 8; ++x) {
            unsigned e = (Flo >> (x * 4)) & 15u;
            nlo |= bsel16(g, e) << (x * 4);
        }
#pragma unroll
        for (int x = 0; x < 8; ++x) {
            unsigned e = (Fhi >> (x * 4)) & 15u;
            nhi |= bsel16(g, e) << (x * 4);
        }
        Flo = nlo; Fhi = nhi;
    }
    slo[j] = Flo; shi[j] = Fhi;
    slo[j + 256] = 0x76543210u; shi[j + 256] = 0xfedcba98u;
    __syncthreads();
    for (int off = 1; off < 256; off <<= 1) {
        unsigned alo = slo[j], ahi = shi[j];
        unsigned blo = slo[j + off], bhi = shi[j + off];
        __syncthreads();
        unsigned nlo = 0, nhi = 0;
#pragma unroll
        for (int x = 0; x < 8; ++x) {
            unsigned e = (blo >> (x * 4)) & 15u;
            unsigned rr = ((e < 8u ? alo : ahi) >> ((e & 7u) * 4u)) & 15u;
            nlo |= rr << (x * 4);
        }
#pragma unroll
        for (int x = 0; x < 8; ++x) {
            unsigned e = (bhi >> (x * 4)) & 15u;
            unsigned rr = ((e < 8u ? alo : ahi) >> ((e & 7u) * 4u)) & 15u;
            nhi |= rr << (x * 4);
        }
        slo[j] = nlo; shi[j] = nhi;
        __syncthreads();
    }
    int idl = sid;
    unsigned plo = slo[j + 1], phi = shi[j + 1];
    unsigned x = (((unsigned)idl < 8u ? plo : phi) >> (((unsigned)idl & 7u) * 4u)) & 15u;
    out[32 * j + 31] = (int)x;
    for (int t = 32 * j + 30; t >= 32 * j; --t) {
        x = (unsigned)bp[(size_t)(t + 1) * 16 + x];
        out[t] = (int)x;
    }
}

// ---------------------------------------------------------------------------
extern "C" void kernel_launch(void* const* d_in, const int* in_sizes, int n_in,
                              void* d_out, int out_size, void* d_ws, size_t ws_size,
                              hipStream_t stream) {
    const int*   sent  = (const int*)  d_in[0];
    const float* embed = (const float*)d_in[1];
    const float* wih_f = (const float*)d_in[2];
    const float* whh_f = (const float*)d_in[3];
    const float* bih_f = (const float*)d_in[4];
    const float* bhh_f = (const float*)d_in[5];
    const float* wih_b = (const float*)d_in[6];
    const float* whh_b = (const float*)d_in[7];
    const float* bih_b = (const float*)d_in[8];
    const float* bhh_b = (const float*)d_in[9];
    const float* Wout  = (const float*)d_in[10];
    const float* bout  = (const float*)d_in[11];
    const float* trans = (const float*)d_in[12];
    const float* h0    = (const float*)d_in[13];
    const float* c0    = (const float*)d_in[14];
    int* out = (int*)d_out;

    float* ws_xw   = (float*)d_ws;                                  // 2*T*1024 f
    float* ws_h    = ws_xw + (size_t)2 * T_LEN * G4;                // 2*T*256 f
    float* ws_feat = ws_h + (size_t)2 * T_LEN * HD;                 // T*16 f
    unsigned char* ws_bp = (unsigned char*)(ws_feat + (size_t)T_LEN * NT); // T*16 B

    // sentinel-fill h_hist every launch: 0xFFFFFFFF (-NaN) is unreachable
    // from finite arithmetic; each word is then written exactly once.
    hipMemsetAsync(ws_h, 0xFF, (size_t)2 * T_LEN * HD * sizeof(float), stream);

    dim3 gA(T_LEN / 32, G4 / 128, 2);
    k_gemm_xw<<<gA, 256, 0, stream>>>(sent, embed, wih_f, wih_b,
                                      bih_f, bhh_f, bih_b, bhh_b, ws_xw);
    k_lstm<<<32, 512, 0, stream>>>(whh_f, whh_b, h0, c0, ws_xw, ws_h);
    k_feats<<<128, 256, 0, stream>>>(ws_h, Wout, bout, ws_feat);
    k_viterbi<<<1, 256, 0, stream>>>(ws_feat, trans, out, ws_bp);
}

// Round 10
// 16485.730 us; speedup vs baseline: 1.2418x; 1.0120x over previous
//
#include <hip/hip_runtime.h>
#include <cstdint>
#include <cstddef>

#define T_LEN 8192
#define EMB 256
#define HD 256          // hidden per direction
#define G4 1024         // 4*HD
#define NT 16
#define START_IX 14
#define STOP_IX 15

#define SLICE 16        // h outputs per WG
#define ROWS 64         // gate rows per WG (4 gates x 16)
#define WPAD 260        // 1040B row stride: 16B-aligned (b128) + bank-balanced
#define SENT 0xFFFFFFFFu

// ---------------------------------------------------------------------------
// Phase A: xw[dir][t][r] = emb[dir? T-1-t : t] @ w_ih^T + (b_ih + b_hh)
// grid (T/32, G4/128, 2), block 256   (proven)
// ---------------------------------------------------------------------------
__global__ __launch_bounds__(256) void k_gemm_xw(
    const int* __restrict__ sent, const float* __restrict__ embed,
    const float* __restrict__ wih_f, const float* __restrict__ wih_b,
    const float* __restrict__ bih_f, const float* __restrict__ bhh_f,
    const float* __restrict__ bih_b, const float* __restrict__ bhh_b,
    float* __restrict__ xw)
{
    const int dir = blockIdx.z;
    const float* __restrict__ wih = dir ? wih_b : wih_f;
    const float* __restrict__ bih = dir ? bih_b : bih_f;
    const float* __restrict__ bhh = dir ? bhh_b : bhh_f;
    __shared__ float at[32][65];
    __shared__ float bt[128][65];
    const int t0 = blockIdx.x * 32, r0 = blockIdx.y * 128;
    const int tid = threadIdx.x;
    const int tx = tid & 31, ty = tid >> 5;
    float acc[4][4] = {};
    for (int k0 = 0; k0 < EMB; k0 += 64) {
        for (int i = tid; i < 32 * 64; i += 256) {
            int row = i >> 6, k = i & 63;
            int t = t0 + row;
            int ts = dir ? (T_LEN - 1 - t) : t;
            at[row][k] = embed[(size_t)sent[ts] * EMB + k0 + k];
        }
        for (int i = tid; i < 128 * 64; i += 256) {
            int row = i >> 6, k = i & 63;
            bt[row][k] = wih[(size_t)(r0 + row) * EMB + k0 + k];
        }
        __syncthreads();
#pragma unroll 16
        for (int kc = 0; kc < 64; ++kc) {
            float a[4], b[4];
#pragma unroll
            for (int u = 0; u < 4; ++u) a[u] = at[ty * 4 + u][kc];
#pragma unroll
            for (int u = 0; u < 4; ++u) b[u] = bt[tx * 4 + u][kc];
#pragma unroll
            for (int u = 0; u < 4; ++u)
#pragma unroll
                for (int v = 0; v < 4; ++v) acc[u][v] += a[u] * b[v];
        }
        __syncthreads();
    }
#pragma unroll
    for (int u = 0; u < 4; ++u) {
        int t = t0 + ty * 4 + u;
#pragma unroll
        for (int v = 0; v < 4; ++v) {
            int r = r0 + tx * 4 + v;
            xw[((size_t)dir * T_LEN + t) * G4 + r] = acc[u][v] + bih[r] + bhh[r];
        }
    }
}

// ---------------------------------------------------------------------------
// Dual-path poll. FAST: sc0-only load (bypass L1, serviced by the local
// XCD L2 -- where the producer's plain write-through store landed IF the
// blockIdx%8 XCD heuristic holds) of a step-tagged u64 packet. SLOW (proven
// rounds 2-9): relaxed agent-scope load of the sentinel-poisoned h_hist
// word. Alternate fast/slow until either hits. Packets are self-validating
// (tag==t), h words monotonic (sentinel->final, written once) => any hit is
// THE value; wrong heuristic or wrong sc-bit semantics only delays (slow
// path fires), never corrupts and never deadlocks.
// ---------------------------------------------------------------------------
__device__ __forceinline__ unsigned poll_dual(
    const unsigned long long* __restrict__ fsrc,
    const unsigned* __restrict__ ssrc, unsigned t)
{
#pragma unroll 1
    for (int it = 0; it < (1 << 20); ++it) {
        unsigned long long u;
        asm volatile("global_load_dwordx2 %0, %1, off sc0\n\t"
                     "s_waitcnt vmcnt(0)"
                     : "=v"(u) : "v"(fsrc) : "memory");
        if ((unsigned)(u >> 32) == t) return (unsigned)u;
        unsigned v = __hip_atomic_load(ssrc, __ATOMIC_RELAXED,
                                       __HIP_MEMORY_SCOPE_AGENT);
        if (v != SENT) return v;
    }
    return 0u;   // unreachable in practice (slow path is proven)
}

// ---------------------------------------------------------------------------
// Phase B: LSTM scans. grid 128, block 512; only blockIdx%8 in {0,1} work:
// dir = blockIdx%8, wsl = blockIdx>>3. Under the common round-robin
// XCD = blockIdx%8 mapping, all 16 WGs of a direction share one XCD ->
// mailbox exchange is served by that XCD's L2 (~300cy) instead of MALL
// (~900+). Heuristic-only placement; correctness is carried by the proven
// agent-scope h_hist transport (slow path of poll_dual).
// mbox layout: [dir][parity][prod][j] u64 = (t<<32)|h_bits; parity + the
// all-to-all consumption order bounds producer/consumer skew <2 steps
// (round-3 proof), so a slot is never overwritten before its readers are
// done with the previous parity occupant.
// Matvec/produce unchanged from round 9 (b128 weights, WPAD=260).
// ---------------------------------------------------------------------------
__global__ __launch_bounds__(512) void k_lstm(
    const float* __restrict__ whh_f, const float* __restrict__ whh_b,
    const float* __restrict__ h0, const float* __restrict__ c0,
    const float* __restrict__ xw, float* __restrict__ h_hist,
    unsigned long long* __restrict__ mbox)
{
    const int m = blockIdx.x & 7;
    if (m >= 2) return;                   // idle filler block
    const int dir = m, wsl = blockIdx.x >> 3;
    const float* __restrict__ whh = dir ? whh_b : whh_f;
    const int tid = threadIdx.x;
    const int wave = tid >> 6, lane = tid & 63;

    __shared__ float wlds[ROWS * WPAD];   // 65 KB
    __shared__ float h_lds[256];
    __shared__ float partial[8 * 64];
    __shared__ float xw_lds[2][64];

    // stage weights once: local row r -> global gate-row R
    for (int i = tid; i < ROWS * 256; i += 512) {
        int r = i >> 8, k = i & 255;
        int R = ((r >> 4) << 8) + wsl * SLICE + (r & 15);
        wlds[r * WPAD + k] = whh[(size_t)R * HD + k];
    }
    if (tid < 256) h_lds[tid] = h0[dir * HD + tid];
    if (tid < 64) {
        int R = ((tid >> 4) << 8) + wsl * SLICE + (tid & 15);
        xw_lds[0][tid] = xw[((size_t)dir * T_LEN) * G4 + R];
    }
    float c = 0.f;
    if (wave == 0 && lane < 16) c = c0[dir * HD + wsl * SLICE + lane];
    __syncthreads();

    float* __restrict__ hh = h_hist + (size_t)dir * T_LEN * HD;

    for (int t = 0; t < T_LEN; ++t) {
        const int cur = t & 1, nxt = cur ^ 1;

        // ---- matvec partial: row=lane, k-segment=wave (32 k), b128 ----
        {
            const float4* wr = (const float4*)&wlds[lane * WPAD + wave * 32];
            const float4* hp = (const float4*)&h_lds[wave * 32];
            float a0 = 0.f, a1 = 0.f, a2 = 0.f, a3 = 0.f;
#pragma unroll
            for (int i = 0; i < 8; ++i) {
                float4 wv = wr[i];
                float4 hv = hp[i];
                a0 += wv.x * hv.x;
                a1 += wv.y * hv.y;
                a2 += wv.z * hv.z;
                a3 += wv.w * hv.w;
            }
            partial[wave * 64 + lane] = (a0 + a1) + (a2 + a3);
        }
        __syncthreads();   // B1

        if (wave == 0) {
            // lane = gate-row (g = lane>>4, j = lane&15)
            float z = xw_lds[cur][lane];
#pragma unroll
            for (int s = 0; s < 8; ++s) z += partial[s * 64 + lane];
            float a = ((lane >> 4) == 2) ? tanhf(z) : 1.f / (1.f + expf(-z));
            const int jm = lane & 15;
            float fg = __shfl(a, 16 + jm);
            float gg = __shfl(a, 32 + jm);
            float og = __shfl(a, 48 + jm);
            if (lane < 16) {
                c = fg * c + a * gg;
                float hv = og * tanhf(c);
                h_lds[wsl * SLICE + lane] = hv;
                // FAST: plain write-through store of tagged packet -> local L2
                unsigned long long pkt =
                    ((unsigned long long)(unsigned)t << 32)
                    | (unsigned long long)__float_as_uint(hv);
                mbox[(((size_t)dir * 2 + cur) * 16 + wsl) * 16 + lane] = pkt;
                // SLOW (proven): agent-scope store of the bare value
                __hip_atomic_store(
                    (unsigned*)&hh[(size_t)t * HD + wsl * SLICE + lane],
                    __float_as_uint(hv),
                    __ATOMIC_RELAXED, __HIP_MEMORY_SCOPE_AGENT);
            }
        } else if (wave <= 4) {
            // poll remote slices; own slice produced locally
            const int idx = (wave - 1) * 64 + lane;   // 0..255
            const int s = idx >> 4, j = idx & 15;
            if (s != wsl) {
                unsigned v = poll_dual(
                    &mbox[(((size_t)dir * 2 + cur) * 16 + s) * 16 + j],
                    (const unsigned*)&hh[(size_t)t * HD + s * SLICE + j],
                    (unsigned)t);
                h_lds[s * SLICE + j] = __uint_as_float(v);
            }
        } else if (wave == 5) {
            if (t + 1 < T_LEN) {
                int R = ((lane >> 4) << 8) + wsl * SLICE + (lane & 15);
                xw_lds[nxt][lane] =
                    xw[((size_t)dir * T_LEN + (t + 1)) * G4 + R];
            }
        }
        __syncthreads();   // B2
    }
}

// ---------------------------------------------------------------------------
// Phase C: feats. 4-way tag split, 128 WGs. W_out staged in LDS.
// ---------------------------------------------------------------------------
__global__ __launch_bounds__(256) void k_feats(
    const float* __restrict__ h_hist, const float* __restrict__ Wout,
    const float* __restrict__ bout, float* __restrict__ feats)
{
    __shared__ float wlds[16][512];
    const int tid = threadIdx.x;
    for (int i = tid; i < 16 * 512; i += 256) wlds[i >> 9][i & 511] = Wout[i];
    __syncthreads();
    const int idx = blockIdx.x * 256 + tid;          // 0..32767
    const int t = idx >> 2, tg = (idx & 3) * 4;      // 4 tags per thread
    const float4* hf = (const float4*)(h_hist + (size_t)t * HD);
    const float4* hb = (const float4*)(h_hist + (size_t)(T_LEN + (T_LEN - 1 - t)) * HD);
    float acc[4];
#pragma unroll
    for (int g = 0; g < 4; ++g) acc[g] = bout[tg + g];
    for (int k = 0; k < 64; ++k) {
        float4 a = hf[k];
#pragma unroll
        for (int g = 0; g < 4; ++g) {
            float4 b = *(const float4*)&wlds[tg + g][k * 4];
            acc[g] += a.x * b.x + a.y * b.y + a.z * b.z + a.w * b.w;
        }
    }
    for (int k = 0; k < 64; ++k) {
        float4 a = hb[k];
#pragma unroll
        for (int g = 0; g < 4; ++g) {
            float4 b = *(const float4*)&wlds[tg + g][256 + k * 4];
            acc[g] += a.x * b.x + a.y * b.y + a.z * b.z + a.w * b.w;
        }
    }
#pragma unroll
    for (int g = 0; g < 4; ++g) feats[(size_t)t * NT + tg + g] = acc[g];
}

// ---------------------------------------------------------------------------
// Phase D: Viterbi (proven bit-exact path).
// ---------------------------------------------------------------------------
__device__ __forceinline__ unsigned bsel16(uint4 g, unsigned e) {
    unsigned wd = (e < 8u) ? ((e < 4u) ? g.x : g.y) : ((e < 12u) ? g.z : g.w);
    return (wd >> ((e & 3u) * 8u)) & 15u;
}

__global__ __launch_bounds__(256) void k_viterbi(
    const float* __restrict__ feats, const float* __restrict__ trans,
    int* __restrict__ out, unsigned char* __restrict__ bp)
{
    __shared__ int sid;
    __shared__ unsigned slo[512], shi[512];
    const int tid = threadIdx.x;

    if (tid < 64) {
        const int i = tid & 15, jg = tid >> 4;
        double tr[4];
#pragma unroll
        for (int u = 0; u < 4; ++u) tr[u] = (double)trans[i * 16 + jg * 4 + u];
        double fvn = (i == START_IX) ? 0.0 : -10000.0;
        float fA = feats[i];
        float fB = feats[16 + i];

        for (int t = 0; t < T_LEN; ++t) {
            float fC = (t + 2 < T_LEN) ? feats[(size_t)(t + 2) * NT + i] : 0.f;

            double best = -1e300; int bj = 0;
#pragma unroll
            for (int u = 0; u < 4; ++u) {
                double fvv = __shfl(fvn, jg * 4 + u);
                double v = fvv + tr[u];
                if (v > best) { best = v; bj = jg * 4 + u; }   // first-max
            }
            double ob = __shfl_down(best, 32); int oj = __shfl_down(bj, 32);
            if (ob > best || (ob == best && oj < bj)) { best = ob; bj = oj; }
            ob = __shfl_down(best, 16); oj = __shfl_down(bj, 16);
            if (ob > best || (ob == best && oj < bj)) { best = ob; bj = oj; }

            if (tid < 16) {
                bp[(size_t)t * 16 + i] = (unsigned char)bj;
                fvn = (double)fA + best;
            }
            fA = fB; fB = fC;
        }
        double term = (tid < 16) ? fvn + (double)trans[tid * 16 + STOP_IX] : -1e300;
        int ti = tid;
#pragma unroll
        for (int off = 1; off < 16; off <<= 1) {
            double ov = __shfl_xor(term, off); int oi = __shfl_xor(ti, off);
            if (ov > term || (ov == term && oi < ti)) { term = ov; ti = oi; }
        }
        if (tid == 0) sid = ti;
    }
    __syncthreads();

    const int j = tid;
    unsigned Flo = 0x76543210u, Fhi = 0xfedcba98u;
    for (int t = 32 * j + 31; t >= 32 * j; --t) {
        uint4 g = *(const uint4*)&bp[(size_t)t * 16];
        unsigned nlo = 0, nhi = 0;
#pragma unroll
        for (int x = 0; x < 8; ++x) {
            unsigned e = (Flo >> (x * 4)) & 15u;
            nlo |= bsel16(g, e) << (x * 4);
        }
#pragma unroll
        for (int x = 0; x < 8; ++x) {
            unsigned e = (Fhi >> (x * 4)) & 15u;
            nhi |= bsel16(g, e) << (x * 4);
        }
        Flo = nlo; Fhi = nhi;
    }
    slo[j] = Flo; shi[j] = Fhi;
    slo[j + 256] = 0x76543210u; shi[j + 256] = 0xfedcba98u;
    __syncthreads();
    for (int off = 1; off < 256; off <<= 1) {
        unsigned alo = slo[j], ahi = shi[j];
        unsigned blo = slo[j + off], bhi = shi[j + off];
        __syncthreads();
        unsigned nlo = 0, nhi = 0;
#pragma unroll
        for (int x = 0; x < 8; ++x) {
            unsigned e = (blo >> (x * 4)) & 15u;
            unsigned rr = ((e < 8u ? alo : ahi) >> ((e & 7u) * 4u)) & 15u;
            nlo |= rr << (x * 4);
        }
#pragma unroll
        for (int x = 0; x < 8; ++x) {
            unsigned e = (bhi >> (x * 4)) & 15u;
            unsigned rr = ((e < 8u ? alo : ahi) >> ((e & 7u) * 4u)) & 15u;
            nhi |= rr << (x * 4);
        }
        slo[j] = nlo; shi[j] = nhi;
        __syncthreads();
    }
    int idl = sid;
    unsigned plo = slo[j + 1], phi = shi[j + 1];
    unsigned x = (((unsigned)idl < 8u ? plo : phi) >> (((unsigned)idl & 7u) * 4u)) & 15u;
    out[32 * j + 31] = (int)x;
    for (int t = 32 * j + 30; t >= 32 * j; --t) {
        x = (unsigned)bp[(size_t)(t + 1) * 16 + x];
        out[t] = (int)x;
    }
}

// ---------------------------------------------------------------------------
extern "C" void kernel_launch(void* const* d_in, const int* in_sizes, int n_in,
                              void* d_out, int out_size, void* d_ws, size_t ws_size,
                              hipStream_t stream) {
    const int*   sent  = (const int*)  d_in[0];
    const float* embed = (const float*)d_in[1];
    const float* wih_f = (const float*)d_in[2];
    const float* whh_f = (const float*)d_in[3];
    const float* bih_f = (const float*)d_in[4];
    const float* bhh_f = (const float*)d_in[5];
    const float* wih_b = (const float*)d_in[6];
    const float* whh_b = (const float*)d_in[7];
    const float* bih_b = (const float*)d_in[8];
    const float* bhh_b = (const float*)d_in[9];
    const float* Wout  = (const float*)d_in[10];
    const float* bout  = (const float*)d_in[11];
    const float* trans = (const float*)d_in[12];
    const float* h0    = (const float*)d_in[13];
    const float* c0    = (const float*)d_in[14];
    int* out = (int*)d_out;

    float* ws_xw   = (float*)d_ws;                                  // 2*T*1024 f
    float* ws_h    = ws_xw + (size_t)2 * T_LEN * G4;                // 2*T*256 f
    float* ws_feat = ws_h + (size_t)2 * T_LEN * HD;                 // T*16 f
    unsigned char* ws_bp = (unsigned char*)(ws_feat + (size_t)T_LEN * NT); // T*16 B
    unsigned long long* ws_mbox =
        (unsigned long long*)(ws_bp + (size_t)T_LEN * NT);          // 1024 u64

    // per-launch poison: h_hist sentinel words + mailbox tags (kills
    // cross-replay ABA; both transports self-validating)
    hipMemsetAsync(ws_h, 0xFF, (size_t)2 * T_LEN * HD * sizeof(float), stream);
    hipMemsetAsync(ws_mbox, 0xFF, 1024 * sizeof(unsigned long long), stream);

    dim3 gA(T_LEN / 32, G4 / 128, 2);
    k_gemm_xw<<<gA, 256, 0, stream>>>(sent, embed, wih_f, wih_b,
                                      bih_f, bhh_f, bih_b, bhh_b, ws_xw);
    k_lstm<<<128, 512, 0, stream>>>(whh_f, whh_b, h0, c0, ws_xw, ws_h, ws_mbox);
    k_feats<<<128, 256, 0, stream>>>(ws_h, Wout, bout, ws_feat);
    k_viterbi<<<1, 256, 0, stream>>>(ws_feat, trans, out, ws_bp);
}

// Round 11
// 14974.223 us; speedup vs baseline: 1.3671x; 1.1009x over previous
//
#include <hip/hip_runtime.h>
#include <cstdint>
#include <cstddef>

#define T_LEN 8192
#define EMB 256
#define HD 256          // hidden per direction
#define G4 1024         // 4*HD
#define NT 16
#define START_IX 14
#define STOP_IX 15

#define SLICE 8         // h outputs per WG per direction
#define ROWSD 32        // gate rows per WG per direction (4 gates x 8)
#define WPAD 260        // 1040B row stride: 16B-aligned (b128) + 8-deep bank-balanced
#define SENT 0xFFFFFFFFu
#define NSCAN 32        // scan WGs (blockIdx%8==0), all on XCD0 under validated map

// mbox slot: [dir][parity][producer][j]
#define MB(d, p, s, j) ((((size_t)(d) * 2 + (p)) * 32 + (s)) * 8 + (j))

// ---------------------------------------------------------------------------
// shared-memory union: scan state vs gemm staging (different block roles)
// ---------------------------------------------------------------------------
struct ScanS {
    float wf[ROWSD * WPAD];   // fwd weights (33280 B)
    float wb[ROWSD * WPAD];   // bwd weights
    float hf[256];
    float hb[256];
    float part[ROWSD * 17];   // partial[r][q], pad 17 -> conflict-free column reads
    float xwf[2][ROWSD];
    float xwb[2][ROWSD];
};
struct GemmS {
    float at[32][65];
    float bt[128][65];
};
#define SMEM_BYTES 83968   // > 81920 -> exactly 1 block/CU (256 blocks = 256 CUs)

// ---------------------------------------------------------------------------
// Dual-path poll (proven round 10): FAST sc0 load of step-tagged mbox packet
// (local-XCD L2 when the blockIdx%8 co-location holds -- validated by the
// round-10 FETCH collapse), SLOW relaxed agent load of the sentinel h word.
// Any hit is THE value; wrong placement only delays, never corrupts.
// ---------------------------------------------------------------------------
__device__ __forceinline__ unsigned poll_dual(
    const unsigned long long* __restrict__ fsrc,
    const unsigned* __restrict__ ssrc, unsigned t)
{
#pragma unroll 1
    for (int it = 0; it < (1 << 20); ++it) {
        unsigned long long u;
        asm volatile("global_load_dwordx2 %0, %1, off sc0\n\t"
                     "s_waitcnt vmcnt(0)"
                     : "=v"(u) : "v"(fsrc) : "memory");
        if ((unsigned)(u >> 32) == t) return (unsigned)u;
        unsigned v = __hip_atomic_load(ssrc, __ATOMIC_RELAXED,
                                       __HIP_MEMORY_SCOPE_AGENT);
        if (v != SENT) return v;
    }
    return 0u;   // unreachable in practice (slow path is proven)
}

// sentinel poll of a once-written word (xw; written by gemm filler blocks)
__device__ __forceinline__ unsigned poll_sent(const unsigned* p) {
    unsigned v; int spin = 0;
    do {
        v = __hip_atomic_load(p, __ATOMIC_RELAXED, __HIP_MEMORY_SCOPE_AGENT);
    } while (v == SENT && ++spin < (1 << 20));
    return v;
}

// ---------------------------------------------------------------------------
// Fused kernel. grid 256, block 512.
//  blockIdx%8 == 0  -> scan block, wsl = blockIdx>>3 (0..31): fwd+bwd slice wsl
//  blockIdx%8 != 0  -> gemm filler: computes xw tiles (agent stores; scan
//                      polls xw words against the 0xFF sentinel)
// Scan iteration (4 barriers):
//   mv_f | B1 | produce_f & poll h_b(t-1) & poll xw(t+1) | B2 |
//   mv_b | B3 | produce_b & poll h_f(t)                  | B4
// Exchange latency is paid UNDER the opposite direction's compute.
// Parity-slot safety: a consumer's read of slot (p,s,j) at step t always
// barrier-precedes the producer's overwrite at step t+2 (producer must pass
// its own poll of step t+1, which needs this consumer's t+1 store, which
// barrier-follows this read).
// ---------------------------------------------------------------------------
__global__ __launch_bounds__(512) void k_fused(
    const int* __restrict__ sent, const float* __restrict__ embed,
    const float* __restrict__ wih_f, const float* __restrict__ wih_b,
    const float* __restrict__ bih_f, const float* __restrict__ bhh_f,
    const float* __restrict__ bih_b, const float* __restrict__ bhh_b,
    const float* __restrict__ whh_f, const float* __restrict__ whh_b,
    const float* __restrict__ h0, const float* __restrict__ c0,
    float* __restrict__ xw, float* __restrict__ h_hist,
    unsigned long long* __restrict__ mbox)
{
    __shared__ __align__(16) char smraw[SMEM_BYTES];
    const int tid = threadIdx.x;

    if ((blockIdx.x & 7) != 0) {
        // ================= gemm filler =================
        GemmS* G = (GemmS*)smraw;
        const int f = (blockIdx.x >> 3) * 7 + (blockIdx.x & 7) - 1;  // 0..223
        const int tx = tid & 31, ty = tid >> 5;                      // 32 x 16
        for (int u = f; u < 4096; u += 224) {
            const int t_tile = u >> 4, sub = u & 15;
            const int dir = sub >> 3, r_tile = sub & 7;
            const float* __restrict__ wih = dir ? wih_b : wih_f;
            const float* __restrict__ bih = dir ? bih_b : bih_f;
            const float* __restrict__ bhh = dir ? bhh_b : bhh_f;
            const int t0 = t_tile * 32, r0 = r_tile * 128;
            float acc[2][4] = {};
            for (int k0 = 0; k0 < EMB; k0 += 64) {
                __syncthreads();   // protect staging buffers (prev reads done)
                for (int i = tid; i < 32 * 64; i += 512) {
                    int row = i >> 6, k = i & 63;
                    int t = t0 + row;
                    int ts = dir ? (T_LEN - 1 - t) : t;
                    G->at[row][k] = embed[(size_t)sent[ts] * EMB + k0 + k];
                }
                for (int i = tid; i < 128 * 64; i += 512) {
                    int row = i >> 6, k = i & 63;
                    G->bt[row][k] = wih[(size_t)(r0 + row) * EMB + k0 + k];
                }
                __syncthreads();
#pragma unroll 16
                for (int kc = 0; kc < 64; ++kc) {
                    float a[2], b[4];
#pragma unroll
                    for (int v = 0; v < 2; ++v) a[v] = G->at[ty * 2 + v][kc];
#pragma unroll
                    for (int v = 0; v < 4; ++v) b[v] = G->bt[tx * 4 + v][kc];
#pragma unroll
                    for (int v = 0; v < 2; ++v)
#pragma unroll
                        for (int w = 0; w < 4; ++w) acc[v][w] += a[v] * b[w];
                }
            }
#pragma unroll
            for (int v = 0; v < 2; ++v) {
                int t = t0 + ty * 2 + v;
#pragma unroll
                for (int w = 0; w < 4; ++w) {
                    int r = r0 + tx * 4 + w;
                    float val = acc[v][w] + bih[r] + bhh[r];
                    __hip_atomic_store(
                        (unsigned*)&xw[((size_t)dir * T_LEN + t) * G4 + r],
                        __float_as_uint(val),
                        __ATOMIC_RELAXED, __HIP_MEMORY_SCOPE_AGENT);
                }
            }
        }
        return;
    }

    // ================= scan block =================
    ScanS* S = (ScanS*)smraw;
    const int wsl = blockIdx.x >> 3;      // 0..31
    const int wave = tid >> 6, lane = tid & 63;

    // stage both directions' weights once (33 KB each)
    for (int i = tid; i < ROWSD * 256; i += 512) {
        int r = i >> 8, k = i & 255;
        int R = ((r >> 3) << 8) + wsl * SLICE + (r & 7);
        S->wf[r * WPAD + k] = whh_f[(size_t)R * HD + k];
        S->wb[r * WPAD + k] = whh_b[(size_t)R * HD + k];
    }
    if (tid < 256) { S->hf[tid] = h0[tid]; S->hb[tid] = h0[256 + tid]; }
    float c_f = 0.f, c_b = 0.f;
    if (wave == 0 && lane < 8) {
        c_f = c0[wsl * SLICE + lane];
        c_b = c0[256 + wsl * SLICE + lane];
    }
    // xw(0) for both directions (gemm fillers run concurrently)
    if (tid < 64) {
        int d = tid >> 5, row = tid & 31;
        int R = ((row >> 3) << 8) + wsl * SLICE + (row & 7);
        unsigned v = poll_sent(
            (const unsigned*)&xw[((size_t)d * T_LEN) * G4 + R]);
        (d ? S->xwb : S->xwf)[0][row] = __uint_as_float(v);
    }
    __syncthreads();

    float* __restrict__ hhf = h_hist;
    float* __restrict__ hhb = h_hist + (size_t)T_LEN * HD;

    for (int t = 0; t < T_LEN; ++t) {
        const int cur = t & 1, nxt = cur ^ 1;

        // ---- mv_f: thread (q=tid>>5, r=tid&31), 16 k each, b128 ----
        {
            const int q = tid >> 5, rr = tid & 31;
            const float4* wr = (const float4*)&S->wf[rr * WPAD + q * 16];
            const float4* hp = (const float4*)&S->hf[q * 16];
            float a0 = 0.f, a1 = 0.f, a2 = 0.f, a3 = 0.f;
#pragma unroll
            for (int i = 0; i < 4; ++i) {
                float4 wv = wr[i], hv = hp[i];
                a0 += wv.x * hv.x; a1 += wv.y * hv.y;
                a2 += wv.z * hv.z; a3 += wv.w * hv.w;
            }
            S->part[rr * 17 + q] = (a0 + a1) + (a2 + a3);
        }
        __syncthreads();   // B1

        if (wave == 0) {
            // produce_f
            const int r = lane & 31;
            float z = S->xwf[cur][r];
#pragma unroll
            for (int q = 0; q < 16; ++q) z += S->part[r * 17 + q];
            float a = ((r >> 3) == 2) ? tanhf(z) : 1.f / (1.f + expf(-z));
            const int j = lane & 7;
            float af = __shfl(a, 8 + j);
            float ag = __shfl(a, 16 + j);
            float ao = __shfl(a, 24 + j);
            if (lane < 8) {
                c_f = af * c_f + a * ag;
                float hv = ao * tanhf(c_f);
                S->hf[wsl * SLICE + j] = hv;
                unsigned long long pkt =
                    ((unsigned long long)(unsigned)t << 32)
                    | (unsigned long long)__float_as_uint(hv);
                mbox[MB(0, cur, wsl, j)] = pkt;          // fast (plain, L2)
                __hip_atomic_store(
                    (unsigned*)&hhf[(size_t)t * HD + wsl * SLICE + j],
                    __float_as_uint(hv),
                    __ATOMIC_RELAXED, __HIP_MEMORY_SCOPE_AGENT);
            }
        } else if (wave <= 4) {
            if (t > 0) {   // gather h_b(t-1) (stored last iter phase D)
                const int idx = (wave - 1) * 64 + lane;   // 0..255
                unsigned v = poll_dual(
                    &mbox[MB(1, (t - 1) & 1, idx >> 3, idx & 7)],
                    (const unsigned*)&hhb[(size_t)(t - 1) * HD + idx],
                    (unsigned)(t - 1));
                S->hb[idx] = __uint_as_float(v);
            }
        } else if (wave == 5) {
            if (t + 1 < T_LEN) {   // prefetch xw(t+1), both dirs
                int d = lane >> 5, row = lane & 31;
                int R = ((row >> 3) << 8) + wsl * SLICE + (row & 7);
                unsigned v = poll_sent((const unsigned*)
                    &xw[((size_t)d * T_LEN + t + 1) * G4 + R]);
                (d ? S->xwb : S->xwf)[nxt][row] = __uint_as_float(v);
            }
        }
        __syncthreads();   // B2

        // ---- mv_b ----
        {
            const int q = tid >> 5, rr = tid & 31;
            const float4* wr = (const float4*)&S->wb[rr * WPAD + q * 16];
            const float4* hp = (const float4*)&S->hb[q * 16];
            float a0 = 0.f, a1 = 0.f, a2 = 0.f, a3 = 0.f;
#pragma unroll
            for (int i = 0; i < 4; ++i) {
                float4 wv = wr[i], hv = hp[i];
                a0 += wv.x * hv.x; a1 += wv.y * hv.y;
                a2 += wv.z * hv.z; a3 += wv.w * hv.w;
            }
            S->part[rr * 17 + q] = (a0 + a1) + (a2 + a3);
        }
        __syncthreads();   // B3

        if (wave == 0) {
            // produce_b
            const int r = lane & 31;
            float z = S->xwb[cur][r];
#pragma unroll
            for (int q = 0; q < 16; ++q) z += S->part[r * 17 + q];
            float a = ((r >> 3) == 2) ? tanhf(z) : 1.f / (1.f + expf(-z));
            const int j = lane & 7;
            float af = __shfl(a, 8 + j);
            float ag = __shfl(a, 16 + j);
            float ao = __shfl(a, 24 + j);
            if (lane < 8) {
                c_b = af * c_b + a * ag;
                float hv = ao * tanhf(c_b);
                S->hb[wsl * SLICE + j] = hv;
                unsigned long long pkt =
                    ((unsigned long long)(unsigned)t << 32)
                    | (unsigned long long)__float_as_uint(hv);
                mbox[MB(1, cur, wsl, j)] = pkt;
                __hip_atomic_store(
                    (unsigned*)&hhb[(size_t)t * HD + wsl * SLICE + j],
                    __float_as_uint(hv),
                    __ATOMIC_RELAXED, __HIP_MEMORY_SCOPE_AGENT);
            }
        } else if (wave <= 4) {
            // gather h_f(t) (stored this iter phase B, ~2 phases ago)
            const int idx = (wave - 1) * 64 + lane;
            unsigned v = poll_dual(
                &mbox[MB(0, cur, idx >> 3, idx & 7)],
                (const unsigned*)&hhf[(size_t)t * HD + idx], (unsigned)t);
            S->hf[idx] = __uint_as_float(v);
        }
        __syncthreads();   // B4
    }
}

// ---------------------------------------------------------------------------
// Phase C: feats. 4-way tag split, 128 WGs. W_out staged in LDS.
// ---------------------------------------------------------------------------
__global__ __launch_bounds__(256) void k_feats(
    const float* __restrict__ h_hist, const float* __restrict__ Wout,
    const float* __restrict__ bout, float* __restrict__ feats)
{
    __shared__ float wlds[16][512];
    const int tid = threadIdx.x;
    for (int i = tid; i < 16 * 512; i += 256) wlds[i >> 9][i & 511] = Wout[i];
    __syncthreads();
    const int idx = blockIdx.x * 256 + tid;          // 0..32767
    const int t = idx >> 2, tg = (idx & 3) * 4;      // 4 tags per thread
    const float4* hf = (const float4*)(h_hist + (size_t)t * HD);
    const float4* hb = (const float4*)(h_hist + (size_t)(T_LEN + (T_LEN - 1 - t)) * HD);
    float acc[4];
#pragma unroll
    for (int g = 0; g < 4; ++g) acc[g] = bout[tg + g];
    for (int k = 0; k < 64; ++k) {
        float4 a = hf[k];
#pragma unroll
        for (int g = 0; g < 4; ++g) {
            float4 b = *(const float4*)&wlds[tg + g][k * 4];
            acc[g] += a.x * b.x + a.y * b.y + a.z * b.z + a.w * b.w;
        }
    }
    for (int k = 0; k < 64; ++k) {
        float4 a = hb[k];
#pragma unroll
        for (int g = 0; g < 4; ++g) {
            float4 b = *(const float4*)&wlds[tg + g][256 + k * 4];
            acc[g] += a.x * b.x + a.y * b.y + a.z * b.z + a.w * b.w;
        }
    }
#pragma unroll
    for (int g = 0; g < 4; ++g) feats[(size_t)t * NT + tg + g] = acc[g];
}

// ---------------------------------------------------------------------------
// Phase D: Viterbi (proven bit-exact path).
// ---------------------------------------------------------------------------
__device__ __forceinline__ unsigned bsel16(uint4 g, unsigned e) {
    unsigned wd = (e < 8u) ? ((e < 4u) ? g.x : g.y) : ((e < 12u) ? g.z : g.w);
    return (wd >> ((e & 3u) * 8u)) & 15u;
}

__global__ __launch_bounds__(256) void k_viterbi(
    const float* __restrict__ feats, const float* __restrict__ trans,
    int* __restrict__ out, unsigned char* __restrict__ bp)
{
    __shared__ int sid;
    __shared__ unsigned slo[512], shi[512];
    const int tid = threadIdx.x;

    if (tid < 64) {
        const int i = tid & 15, jg = tid >> 4;
        double tr[4];
#pragma unroll
        for (int u = 0; u < 4; ++u) tr[u] = (double)trans[i * 16 + jg * 4 + u];
        double fvn = (i == START_IX) ? 0.0 : -10000.0;
        float fA = feats[i];
        float fB = feats[16 + i];

        for (int t = 0; t < T_LEN; ++t) {
            float fC = (t + 2 < T_LEN) ? feats[(size_t)(t + 2) * NT + i] : 0.f;

            double best = -1e300; int bj = 0;
#pragma unroll
            for (int u = 0; u < 4; ++u) {
                double fvv = __shfl(fvn, jg * 4 + u);
                double v = fvv + tr[u];
                if (v > best) { best = v; bj = jg * 4 + u; }   // first-max
            }
            double ob = __shfl_down(best, 32); int oj = __shfl_down(bj, 32);
            if (ob > best || (ob == best && oj < bj)) { best = ob; bj = oj; }
            ob = __shfl_down(best, 16); oj = __shfl_down(bj, 16);
            if (ob > best || (ob == best && oj < bj)) { best = ob; bj = oj; }

            if (tid < 16) {
                bp[(size_t)t * 16 + i] = (unsigned char)bj;
                fvn = (double)fA + best;
            }
            fA = fB; fB = fC;
        }
        double term = (tid < 16) ? fvn + (double)trans[tid * 16 + STOP_IX] : -1e300;
        int ti = tid;
#pragma unroll
        for (int off = 1; off < 16; off <<= 1) {
            double ov = __shfl_xor(term, off); int oi = __shfl_xor(ti, off);
            if (ov > term || (ov == term && oi < ti)) { term = ov; ti = oi; }
        }
        if (tid == 0) sid = ti;
    }
    __syncthreads();

    const int j = tid;
    unsigned Flo = 0x76543210u, Fhi = 0xfedcba98u;
    for (int t = 32 * j + 31; t >= 32 * j; --t) {
        uint4 g = *(const uint4*)&bp[(size_t)t * 16];
        unsigned nlo = 0, nhi = 0;
#pragma unroll
        for (int x = 0; x < 8; ++x) {
            unsigned e = (Flo >> (x * 4)) & 15u;
            nlo |= bsel16(g, e) << (x * 4);
        }
#pragma unroll
        for (int x = 0; x < 8; ++x) {
            unsigned e = (Fhi >> (x * 4)) & 15u;
            nhi |= bsel16(g, e) << (x * 4);
        }
        Flo = nlo; Fhi = nhi;
    }
    slo[j] = Flo; shi[j] = Fhi;
    slo[j + 256] = 0x76543210u; shi[j + 256] = 0xfedcba98u;
    __syncthreads();
    for (int off = 1; off < 256; off <<= 1) {
        unsigned alo = slo[j], ahi = shi[j];
        unsigned blo = slo[j + off], bhi = shi[j + off];
        __syncthreads();
        unsigned nlo = 0, nhi = 0;
#pragma unroll
        for (int x = 0; x < 8; ++x) {
            unsigned e = (blo >> (x * 4)) & 15u;
            unsigned rr = ((e < 8u ? alo : ahi) >> ((e & 7u) * 4u)) & 15u;
            nlo |= rr << (x * 4);
        }
#pragma unroll
        for (int x = 0; x < 8; ++x) {
            unsigned e = (bhi >> (x * 4)) & 15u;
            unsigned rr = ((e < 8u ? alo : ahi) >> ((e & 7u) * 4u)) & 15u;
            nhi |= rr << (x * 4);
        }
        slo[j] = nlo; shi[j] = nhi;
        __syncthreads();
    }
    int idl = sid;
    unsigned plo = slo[j + 1], phi = shi[j + 1];
    unsigned x = (((unsigned)idl < 8u ? plo : phi) >> (((unsigned)idl & 7u) * 4u)) & 15u;
    out[32 * j + 31] = (int)x;
    for (int t = 32 * j + 30; t >= 32 * j; --t) {
        x = (unsigned)bp[(size_t)(t + 1) * 16 + x];
        out[t] = (int)x;
    }
}

// ---------------------------------------------------------------------------
extern "C" void kernel_launch(void* const* d_in, const int* in_sizes, int n_in,
                              void* d_out, int out_size, void* d_ws, size_t ws_size,
                              hipStream_t stream) {
    const int*   sent  = (const int*)  d_in[0];
    const float* embed = (const float*)d_in[1];
    const float* wih_f = (const float*)d_in[2];
    const float* whh_f = (const float*)d_in[3];
    const float* bih_f = (const float*)d_in[4];
    const float* bhh_f = (const float*)d_in[5];
    const float* wih_b = (const float*)d_in[6];
    const float* whh_b = (const float*)d_in[7];
    const float* bih_b = (const float*)d_in[8];
    const float* bhh_b = (const float*)d_in[9];
    const float* Wout  = (const float*)d_in[10];
    const float* bout  = (const float*)d_in[11];
    const float* trans = (const float*)d_in[12];
    const float* h0    = (const float*)d_in[13];
    const float* c0    = (const float*)d_in[14];
    int* out = (int*)d_out;

    float* ws_xw   = (float*)d_ws;                                  // 2*T*1024 f
    float* ws_h    = ws_xw + (size_t)2 * T_LEN * G4;                // 2*T*256 f
    float* ws_feat = ws_h + (size_t)2 * T_LEN * HD;                 // T*16 f
    unsigned char* ws_bp = (unsigned char*)(ws_feat + (size_t)T_LEN * NT); // T*16 B
    unsigned long long* ws_mbox =
        (unsigned long long*)(ws_bp + (size_t)T_LEN * NT);          // 1024 u64

    // per-launch poison (replay-safe): xw + h_hist sentinel words, mbox tags
    hipMemsetAsync(ws_xw, 0xFF, (size_t)2 * T_LEN * G4 * sizeof(float), stream);
    hipMemsetAsync(ws_h, 0xFF, (size_t)2 * T_LEN * HD * sizeof(float), stream);
    hipMemsetAsync(ws_mbox, 0xFF, 1024 * sizeof(unsigned long long), stream);

    k_fused<<<256, 512, 0, stream>>>(sent, embed, wih_f, wih_b,
                                     bih_f, bhh_f, bih_b, bhh_b,
                                     whh_f, whh_b, h0, c0,
                                     ws_xw, ws_h, ws_mbox);
    k_feats<<<128, 256, 0, stream>>>(ws_h, Wout, bout, ws_feat);
    k_viterbi<<<1, 256, 0, stream>>>(ws_feat, trans, out, ws_bp);
}